// Round 23
// baseline (971.657 us; speedup 1.0000x reference)
//
#include <hip/hip_runtime.h>

typedef unsigned short u16;
typedef unsigned int   u32;
typedef __attribute__((ext_vector_type(8))) short bf16x8;  // 8 bf16 (4 VGPRs)
typedef __attribute__((ext_vector_type(4))) float f32x4;   // 4 fp32

// ---------- bf16 helpers (manual, RNE) ----------
__device__ __forceinline__ float bf2f(u16 u) { return __uint_as_float(((u32)u) << 16); }
__device__ __forceinline__ float bflo(u32 u) { return __uint_as_float(u << 16); }
__device__ __forceinline__ float bfhi(u32 u) { return __uint_as_float(u & 0xffff0000u); }
__device__ __forceinline__ u16 f2bf(float f) {
    u32 x = __float_as_uint(f);
    x += 0x7fffu + ((x >> 16) & 1u);   // round-to-nearest-even
    return (u16)(x >> 16);
}
// BN1+ReLU on a packed bf16 pair -- bit-identical to the old bnpack_kernel
__device__ __forceinline__ u32 bnpair(u32 v, float s0, float s1, float h0, float h1) {
    float a = fmaxf(0.f, fmaf(s0, bflo(v), h0));
    float c = fmaxf(0.f, fmaf(s1, bfhi(v), h1));
    return (u32)f2bf(a) | ((u32)f2bf(c) << 16);
}
// ---------- fp16 helpers (hardware cvt, RNE) ----------
__device__ __forceinline__ u16 f2h(float f) {
    _Float16 h = (_Float16)f;
    return __builtin_bit_cast(u16, h);
}
__device__ __forceinline__ float h2f(u16 u) {
    return (float)__builtin_bit_cast(_Float16, u);
}

// ---------- prep: conv1 + BOTH repacks + s0g zero in ONE dispatch ----------
// blocks 0..511      : conv1 (9x9 s1) + bias + bf16 store + BN1 stats (long pole, first)
// blocks 512..21247  : w2r[kk][ccc][co][cil] bf16 repack (5,308,416 elems)
// blocks 21248..27007: Wt2[i][je][d] f32 repack (1,474,560 elems)
// blocks 27008..27327: zero s0g (first touched by uhat, 2 dispatches later)
__global__ __launch_bounds__(256) void prep_kernel(const float* __restrict__ x,
                                                   const float* __restrict__ w1,
                                                   const float* __restrict__ b1,
                                                   u16* __restrict__ y,
                                                   float* __restrict__ sum1,
                                                   float* __restrict__ sumsq1,
                                                   const float* __restrict__ w2,
                                                   u16* __restrict__ w2r,
                                                   const float* __restrict__ W,
                                                   float* __restrict__ Wt2,
                                                   float* __restrict__ s0g) {
    __shared__ float xs[784];
    const int blk = blockIdx.x;
    const int t = threadIdx.x;
    if (blk < 512) {
        // ---- conv1, image b = blk ----
        const int b = blk;
        const float* xb = x + (size_t)b * 784;
        for (int idx = t; idx < 784; idx += 256) xs[idx] = xb[idx];
        float w[81];
#pragma unroll
        for (int q = 0; q < 81; ++q) w[q] = w1[(size_t)t * 81 + q];
        const float bias = b1[t];
        __syncthreads();

        float sl = 0.f, ssl = 0.f;
        u16* yb = y + (size_t)b * 400 * 256 + t;   // channels-last, stride 256
        for (int oh = 0; oh < 20; ++oh) {
            float acc[20];
#pragma unroll
            for (int ow = 0; ow < 20; ++ow) acc[ow] = bias;
#pragma unroll
            for (int kh = 0; kh < 9; ++kh) {
                const float4* rp = (const float4*)(&xs[(oh + kh) * 28]);
                float r[28];
#pragma unroll
                for (int k4 = 0; k4 < 7; ++k4) {
                    float4 f = rp[k4];
                    r[k4 * 4 + 0] = f.x; r[k4 * 4 + 1] = f.y;
                    r[k4 * 4 + 2] = f.z; r[k4 * 4 + 3] = f.w;
                }
#pragma unroll
                for (int kw = 0; kw < 9; ++kw) {
                    const float wv = w[kh * 9 + kw];
#pragma unroll
                    for (int ow = 0; ow < 20; ++ow)
                        acc[ow] = fmaf(wv, r[ow + kw], acc[ow]);
                }
            }
#pragma unroll
            for (int ow = 0; ow < 20; ++ow) {
                u16 q = f2bf(acc[ow]);
                float rv = bf2f(q);
                sl += rv; ssl += rv * rv;
                yb[(size_t)(oh * 20 + ow) * 256] = q;
            }
        }
        atomicAdd(&sum1[t], sl);
        atomicAdd(&sumsq1[t], ssl);
    } else if (blk < 21248) {
        // ---- w2r repack ----
        int idx = (blk - 512) * 256 + t;
        int cil = idx & 31;
        int co  = (idx >> 5) & 255;
        int ccc = (idx >> 13) & 7;
        int kk  = idx >> 16;
        int ci  = ccc * 32 + cil;
        w2r[idx] = f2bf(w2[(size_t)co * 20736 + (size_t)ci * 81 + kk]);
    } else if (blk < 27008) {
        // ---- Wt2 repack ----
        int idx = (blk - 21248) * 256 + t;
        int d  = idx & 7;
        int je = (idx >> 3) % 160;
        int i  = idx / 1280;
        int j = je >> 4, e = je & 15;
        Wt2[idx] = W[(((size_t)j * 1152 + i) * 8 + d) * 16 + e];
    } else {
        // ---- s0g zero (81,920 floats = 320 blocks x 256) ----
        s0g[(blk - 27008) * 256 + t] = 0.f;
    }
}

// ---------- conv2: implicit-im2col bf16 MFMA, kh-UNION staging + fused BN1 ----------
// FINAL measured-best structure (session 1222 -> ~930 us):
//   round-3 pipeline (transient staging, 2 barriers/stage, depth-3 A-frag /
//   depth-2 B-frag register pipeline)
// + r12 BN1/ReLU staging fusion + r14 inline finalize_bn1
// + r20 T5 s_setprio around MFMA bursts (429->411 us)
// + r21 XCD co-partition decode (411->402 us, 5-sample A/B)
// r23 (this round): __launch_bounds__(256,2) -> (256,1). Since r20 the
// allocator snapped to the 128-VGPR occupancy boundary and spilled ~2 MB
// (WRITE 22.5->24.6 MB); LDS (2x65,280 B) pins occupancy to 2 blocks/CU for
// any VGPR <= 256, so the relaxed hint lets regalloc take ~132-160 VGPR
// spill-free at unchanged occupancy. No semantic change -> bit-identical.
__global__ __launch_bounds__(256, 1) void conv2_mfma_kernel(const u16* __restrict__ y,
                                                            const u16* __restrict__ w2r,
                                                            const float* __restrict__ b2,
                                                            const float* __restrict__ sum1,
                                                            const float* __restrict__ sumsq1,
                                                            const float* __restrict__ g1,
                                                            const float* __restrict__ be1,
                                                            float* __restrict__ z_raw,
                                                            float* __restrict__ sum2,
                                                            float* __restrict__ sumsq2) {
    __shared__ __align__(16) u16 stg[240 * 136];   // 65,280 B (pad-136: measured best)
    const int blk = blockIdx.x;
    const int cb = ((blk & 7) >> 2) * 128;         // XCD co-partition
    const int g  = ((blk >> 3) << 2) | (blk & 3);  // image pair, bijective per cb
    const int b0 = g * 2;
    const int t = threadIdx.x;
    const int wave = t >> 6, lane = t & 63;
    const int n16 = lane & 15, quad = lane >> 4;
    const int img = wave & 1, c64 = wave >> 1;     // wave: image, 64-co half of slice

    f32x4 zero = {0.f, 0.f, 0.f, 0.f};
    f32x4 acc[4][3];
#pragma unroll
    for (int ct = 0; ct < 4; ++ct)
#pragma unroll
        for (int pt = 0; pt < 3; ++pt) acc[ct][pt] = zero;

    // per-lane B-row bases (clamped: pos>=36 lanes read pos=35's valid data;
    // their acc is garbage but never stored -- epilogue guards pos<36)
    int brow[3];
#pragma unroll
    for (int pt = 0; pt < 3; ++pt) {
        int pos = pt * 16 + n16; if (pos > 35) pos = 35;
        const int oh = (pos * 43) >> 8;            // pos/6
        const int ow = pos - oh * 6;
        brow[pt] = (img * 6 + oh) * 20 + 2 * ow;   // + kw at use site
    }

    const int laneoff = (cb + c64 * 64 + n16) * 32 + quad * 8;   // weight lane offset
    const int c16t = t & 15;                       // staging channel group (stage-invariant)

    bf16x8 abuf[3][4];   // depth-3 A-frag pipeline (48 VGPR, 3-itt live range)
    bf16x8 bbuf[2][3];   // depth-2 B-frag pipeline (24 VGPR, 2-itt live range)

    // itt = kw*4 + ccc, 0..35; base = w2r + kh*589824 + cp*32768 + laneoff
    auto loadA = [&](bf16x8 (&dst)[4], const u16* basep, int ittv) {
        const u16* wa = basep + (ittv >> 2) * 65536 + (ittv & 3) * 8192;
#pragma unroll
        for (int ct = 0; ct < 4; ++ct)
            dst[ct] = *((const bf16x8*)(wa + ct * 512));         // 16 co * 32 ci
    };
    auto loadB = [&](bf16x8 (&dst)[3], int ittv) {
        const int kw = ittv >> 2, ccc = ittv & 3;
#pragma unroll
        for (int pt = 0; pt < 3; ++pt)
            dst[pt] = *((const bf16x8*)(stg + (brow[pt] + kw) * 136
                                        + ccc * 32 + quad * 8));
    };

    // prologue: stage-0 A preloads (itt 0,1,2)
    {
        const u16* w0 = w2r + laneoff;             // kh=0, cp=0
        loadA(abuf[0], w0, 0);
        loadA(abuf[1], w0, 1);
        loadA(abuf[2], w0, 2);
    }

    for (int kh = 0; kh < 9; ++kh) {
        for (int cp = 0; cp < 2; ++cp) {
            __syncthreads();                       // prev compute done reading stg
            // transient staging + fused BN1/ReLU: 240 rows x 256 B, 15
            // uint4/thread; BN constants for this thread's 8 channels
            // computed inline from BN1 stats (transient, bit-identical to
            // the old finalize_bn kernel)
            {
                const int chb = cp * 128 + c16t * 8;
                float scv[8], shv[8];
#pragma unroll
                for (int cc = 0; cc < 8; ++cc) {
                    const float m   = sum1[chb + cc] * (1.f / 204800.f);
                    const float var = sumsq1[chb + cc] * (1.f / 204800.f) - m * m;
                    const float sc  = g1[chb + cc] * rsqrtf(var + 1e-5f);
                    scv[cc] = sc;
                    shv[cc] = be1[chb + cc] - m * sc;
                }
#pragma unroll
                for (int q = 0; q < 15; ++q) {
                    const int v = t + q * 256;     // < 3840
                    const int rI = v >> 4, c16 = v & 15;   // c16 == c16t
                    const int i2 = (rI >= 120) ? 1 : 0;
                    const int rr = rI - i2 * 120;
                    const int oh = rr / 20;
                    const int iw = rr - oh * 20;
                    const int ip = (2 * oh + kh) * 20 + iw;
                    uint4 d = *((const uint4*)(y + ((size_t)(b0 + i2) * 400 + ip) * 256
                                               + cp * 128 + c16 * 8));
                    d.x = bnpair(d.x, scv[0], scv[1], shv[0], shv[1]);
                    d.y = bnpair(d.y, scv[2], scv[3], shv[2], shv[3]);
                    d.z = bnpair(d.z, scv[4], scv[5], shv[4], shv[5]);
                    d.w = bnpair(d.w, scv[6], scv[7], shv[6], shv[7]);
                    *((uint4*)(stg + rI * 136 + c16 * 8)) = d;
                }
            }
            __syncthreads();

            const int khn = (cp == 1) ? kh + 1 : kh;   // next stage coords
            const int cpn = cp ^ 1;
            const u16* wbase = w2r + (size_t)kh * 589824 + (size_t)cp * 32768 + laneoff;
            const u16* wnext = w2r + (size_t)khn * 589824 + (size_t)cpn * 32768 + laneoff;

            loadB(bbuf[0], 0);                     // B preloads for itt 0,1
            loadB(bbuf[1], 1);

#pragma unroll
            for (int itt = 0; itt < 36; ++itt) {
                const int a_i = itt % 3, b_i = itt % 2;
                __builtin_amdgcn_s_setprio(1);     // T5: favor MFMA-issuing wave
#pragma unroll
                for (int ct = 0; ct < 4; ++ct)
#pragma unroll
                    for (int pt = 0; pt < 3; ++pt)
                        acc[ct][pt] = __builtin_amdgcn_mfma_f32_16x16x32_bf16(
                            abuf[a_i][ct], bbuf[b_i][pt], acc[ct][pt], 0, 0, 0);
                __builtin_amdgcn_s_setprio(0);
                // rotate: A prefetch distance 3 (tail wraps into next stage),
                // B prefetch distance 2 (LDS, stage-local)
                if (itt < 33) loadA(abuf[a_i], wbase, itt + 3);
                else          loadA(abuf[a_i], wnext, itt + 3 - 36);
                if (itt < 34) loadB(bbuf[b_i], itt + 2);
            }
        }
    }

    // epilogue: bias, store z[b0+img][co][36], BN2 stats
#pragma unroll
    for (int ct = 0; ct < 4; ++ct) {
#pragma unroll
        for (int r = 0; r < 4; ++r) {
            const int co = cb + c64 * 64 + ct * 16 + quad * 4 + r;
            const float bias = b2[co];
            float s = 0.f, ss = 0.f;
#pragma unroll
            for (int pt = 0; pt < 3; ++pt) {
                const int pos = pt * 16 + n16;
                if (pos < 36) {
                    float v = acc[ct][pt][r] + bias;
                    z_raw[((size_t)(b0 + img) * 256 + co) * 36 + pos] = v;
                    s += v; ss += v * v;
                }
            }
#pragma unroll
            for (int m = 1; m < 16; m <<= 1) {
                s  += __shfl_xor(s,  m, 64);
                ss += __shfl_xor(ss, m, 64);
            }
            if (n16 == 0) { atomicAdd(&sum2[co], s); atomicAdd(&sumsq2[co], ss); }
        }
    }
}

// ---------- u_hat: fused BN2+ReLU staging (ubuild + finalize_bn2 eliminated) ----------
// r13: stage directly from z_raw (index identity), BN2+ReLU inline, fp16
// quantization reproduced bit-identically via h2f(f2h(val)). r15: the
// block's 32 channels' (sc,sh) computed ONCE by threads 0-31 into a 256 B
// LDS table (bit-identical), staging reads via broadcast.
__global__ __launch_bounds__(256) void uhat_kernel(const float* __restrict__ z_raw,
                                                   const float* __restrict__ sum2,
                                                   const float* __restrict__ sumsq2,
                                                   const float* __restrict__ g2,
                                                   const float* __restrict__ be2,
                                                   const float* __restrict__ Wt2,
                                                   u16* __restrict__ u_hat,
                                                   float* __restrict__ s0g) {
    __shared__ float utl[8 * 8 * 144];    // [bb][d][ii], 36 KB
    __shared__ float scl[32], shl[32];    // BN2 consts for this block's channels
    const int bg = blockIdx.x >> 3;       // 64 image-groups of 8
    const int ic = blockIdx.x & 7;        // 8 i-chunks of 144
    const int b0 = bg * 8, i0 = ic * 144;
    if (threadIdx.x < 32) {
        const int d = threadIdx.x >> 2, j = threadIdx.x & 3;
        const int c = d * 32 + ic * 4 + j;
        const float m   = sum2[c] * (1.f / 18432.f);
        const float var = sumsq2[c] * (1.f / 18432.f) - m * m;
        const float sc  = g2[c] * rsqrtf(var + 1e-5f);
        scl[threadIdx.x] = sc;
        shl[threadIdx.x] = be2[c] - m * sc;
    }
    __syncthreads();
    for (int v = threadIdx.x; v < 8 * 8 * 144; v += 256) {
        int ii = v % 144; int d = (v / 144) & 7; int bb = v / 1152;
        const int li = d * 4 + ii / 36;   // LDS table index
        float z = z_raw[(size_t)(b0 + bb) * 9216 + d * 1152 + i0 + ii];
        float val = fmaxf(0.f, fmaf(scl[li], z, shl[li]));
        utl[v] = h2f(f2h(val));           // bit-identical to ubuild's fp16 round
    }
    __syncthreads();
    for (int q = 0; q < 90; ++q) {
        int o = q * 256 + threadIdx.x;    // 144*160 = 23040 = 90*256
        int ii = o / 160, je = o - ii * 160;
        const float* wp = Wt2 + ((size_t)(i0 + ii) * 160 + je) * 8;
        float w[8];
#pragma unroll
        for (int d = 0; d < 8; ++d) w[d] = wp[d];
#pragma unroll
        for (int bb = 0; bb < 8; ++bb) {
            float acc = 0.f;
#pragma unroll
            for (int d = 0; d < 8; ++d) acc = fmaf(w[d], utl[bb * 1152 + d * 144 + ii], acc);
            u_hat[(size_t)(b0 + bb) * 184320 + (size_t)(i0 + ii) * 160 + je] = f2h(acc);
        }
    }
    __syncthreads();   // drains stores (compiler emits vmcnt(0) before barrier)
    // s0 partials: 1280 (bb,je) pairs, 5 per thread; re-read own L2-hot tile
#pragma unroll
    for (int p = 0; p < 5; ++p) {
        const int pair = p * 256 + threadIdx.x;
        const int bb = pair / 160, je = pair - (pair / 160) * 160;
        const u16* up = u_hat + (size_t)(b0 + bb) * 184320 + (size_t)i0 * 160 + je;
        float s = 0.f;
        for (int ii = 0; ii < 144; ++ii) s += h2f(up[(size_t)ii * 160]);
        atomicAdd(&s0g[(size_t)(b0 + bb) * 160 + je], s);
    }
}

// ---------- fused routing, iterations 1..4 (iter-0 s precomputed), double-buffered ----------
// Round-9 form (in every session best since): b-logits in LDS (pad-11 rows,
// conflict-free), phase B 4-way split accumulators. Session evidence:
// 2-blocks/CU via <=80 KB LDS does not materialize (r16); register b-logits
// at 384 thr spill (r15/r17); global-read routing thrashes HBM (r17).
__global__ __launch_bounds__(384) void routing_kernel(const u16* __restrict__ u_hat,
                                                      const float* __restrict__ s0g,
                                                      float* __restrict__ out) {
    __shared__ __align__(16) u16 uhs[2][96 * 168]; // 2 x 31.5 KB, row pad 168
    __shared__ float cl[10 * 96];
    __shared__ float part[320];
    __shared__ float sv[160];
    __shared__ float bls[12 * 96 * 11];            // b-logits, padded rows of 11
    const int t = threadIdx.x;
    const int b = blockIdx.x;
    const u16* uh = u_hat + (size_t)b * 184320;
    const int hB = (t < 320) ? (t / 160) : 0;
    const int je = (t < 320) ? (t - hB * 160) : 0;
    const int jB = je >> 4;

    // issue chunk-0 loads, then v0 = squash(0.1 * s0)
    uint4 rg[5];
    {
        const u16* src = uh;
#pragma unroll
        for (int q = 0; q < 5; ++q) {
            int v = t + q * 384, r = v / 20, c16 = v - r * 20;
            rg[q] = *((const uint4*)(src + r * 160 + c16 * 8));
        }
    }
    // zero b-logit LDS (pads included)
    for (int v = t; v < 12 * 96 * 11; v += 384) bls[v] = 0.f;
    if (t < 160) sv[t] = 0.1f * s0g[(size_t)b * 160 + t];
    __syncthreads();
    if (t < 10) {
        float n2 = 0.f;
#pragma unroll
        for (int e2 = 0; e2 < 16; ++e2) { float xx = sv[t * 16 + e2]; n2 += xx * xx; }
        float n = sqrtf(n2);
        float f = n / (n2 + 1.f);
#pragma unroll
        for (int e2 = 0; e2 < 16; ++e2) sv[t * 16 + e2] *= f;
    }
    // write chunk 0 into buf 0
#pragma unroll
    for (int q = 0; q < 5; ++q) {
        int v = t + q * 384, r = v / 20, c16 = v - r * 20;
        *((uint4*)(&uhs[0][r * 168 + c16 * 8])) = rg[q];
    }

    for (int k = 1; k <= 4; ++k) {
        float b0a = 0.f, b1a = 0.f, b2a = 0.f, b3a = 0.f;   // split sacc
        for (int c = 0; c < 12; ++c) {
            const int p = c & 1;
            const bool last = (k == 4) && (c == 11);
            __syncthreads();               // buf[p] writes + sv/cl updates visible
            if (!last) {                   // issue next-chunk loads (wraps to 0 across k)
                const int nc = (c == 11) ? 0 : c + 1;
                const u16* src = uh + (size_t)nc * 15360;
#pragma unroll
                for (int q = 0; q < 5; ++q) {
                    int v = t + q * 384, r = v / 20, c16 = v - r * 20;
                    rg[q] = *((const uint4*)(src + r * 160 + c16 * 8));
                }
            }
            if (t < 96) {                  // phase A
                const u16* row = uhs[p] + t * 168;
                float* blrow = &bls[(c * 96 + t) * 11];
                float bj[10];
#pragma unroll
                for (int j = 0; j < 10; ++j) {
                    uint4 a = *((const uint4*)(row + j * 16));
                    uint4 bq = *((const uint4*)(row + j * 16 + 8));
                    const float* vv = &sv[j * 16];
                    float dj = h2f((u16)(a.x & 0xffff)) * vv[0]  + h2f((u16)(a.x >> 16)) * vv[1]
                             + h2f((u16)(a.y & 0xffff)) * vv[2]  + h2f((u16)(a.y >> 16)) * vv[3]
                             + h2f((u16)(a.z & 0xffff)) * vv[4]  + h2f((u16)(a.z >> 16)) * vv[5]
                             + h2f((u16)(a.w & 0xffff)) * vv[6]  + h2f((u16)(a.w >> 16)) * vv[7]
                             + h2f((u16)(bq.x & 0xffff)) * vv[8]  + h2f((u16)(bq.x >> 16)) * vv[9]
                             + h2f((u16)(bq.y & 0xffff)) * vv[10] + h2f((u16)(bq.y >> 16)) * vv[11]
                             + h2f((u16)(bq.z & 0xffff)) * vv[12] + h2f((u16)(bq.z >> 16)) * vv[13]
                             + h2f((u16)(bq.w & 0xffff)) * vv[14] + h2f((u16)(bq.w >> 16)) * vv[15];
                    float nb = blrow[j] + dj;
                    blrow[j] = nb;
                    bj[j] = nb;
                }
                float mx = bj[0];
#pragma unroll
                for (int j = 1; j < 10; ++j) mx = fmaxf(mx, bj[j]);
                float s = 0.f;
#pragma unroll
                for (int j = 0; j < 10; ++j) { bj[j] = __expf(bj[j] - mx); s += bj[j]; }
                float inv = 1.f / s;
#pragma unroll
                for (int j = 0; j < 10; ++j) cl[j * 96 + t] = bj[j] * inv;
            }
            __syncthreads();               // cl visible
            if (t < 320) {                 // phase B: 48 rows, 4-way split acc
                const int r0 = hB * 48;
                const float* clj = &cl[jB * 96 + r0];
                const u16* up = uhs[p] + r0 * 168 + je;
#pragma unroll 3
                for (int il = 0; il < 48; il += 4) {
                    b0a = fmaf(clj[il],     h2f(up[(il)     * 168]), b0a);
                    b1a = fmaf(clj[il + 1], h2f(up[(il + 1) * 168]), b1a);
                    b2a = fmaf(clj[il + 2], h2f(up[(il + 2) * 168]), b2a);
                    b3a = fmaf(clj[il + 3], h2f(up[(il + 3) * 168]), b3a);
                }
            }
            if (!last) {                   // write next chunk into the other buffer
#pragma unroll
                for (int q = 0; q < 5; ++q) {
                    int v = t + q * 384, r = v / 20, c16 = v - r * 20;
                    *((uint4*)(&uhs[p ^ 1][r * 168 + c16 * 8])) = rg[q];
                }
            }
        }
        __syncthreads();
        if (t < 320) part[t] = (b0a + b1a) + (b2a + b3a);
        __syncthreads();
        if (t < 160) sv[t] = part[t] + part[t + 160];
        __syncthreads();
        if (t < 10) {
            float n2 = 0.f;
#pragma unroll
            for (int e2 = 0; e2 < 16; ++e2) { float xx = sv[t * 16 + e2]; n2 += xx * xx; }
            float n = sqrtf(n2);
            float f = n / (n2 + 1.f);
#pragma unroll
            for (int e2 = 0; e2 < 16; ++e2) sv[t * 16 + e2] *= f;
        }
    }
    __syncthreads();
    if (t < 160) out[(size_t)b * 160 + t] = sv[t];
}

extern "C" void kernel_launch(void* const* d_in, const int* in_sizes, int n_in,
                              void* d_out, int out_size, void* d_ws, size_t ws_size,
                              hipStream_t stream) {
    const float* x   = (const float*)d_in[0];
    const float* w1  = (const float*)d_in[1];
    const float* b1  = (const float*)d_in[2];
    const float* g1  = (const float*)d_in[3];
    const float* be1 = (const float*)d_in[4];
    const float* w2  = (const float*)d_in[5];
    const float* b2  = (const float*)d_in[6];
    const float* g2  = (const float*)d_in[7];
    const float* be2 = (const float*)d_in[8];
    const float* W   = (const float*)d_in[9];
    float* out = (float*)d_out;

    // ---- workspace layout (peak 213,524,480 B == proven-safe bound) ----
    const size_t OFF_UHAT = 8192;                       // 188,743,680 B (fp16, full batch)
    const size_t OFF_Y    = 8192;                       // 104,857,600 B (in u_hat region)
    const size_t OFF_W2R  = 104865792ull;               //  10,616,832 B (in u_hat region)
    const size_t OFF_Z    = 126099456ull;               //  18,874,368 B (in u_hat region)
    const size_t OFF_S0   = 198189056ull;               //     327,680 B (s0)
    const size_t OFF_WT   = 207626240ull;               //   5,898,240 B
    const size_t WS_NEED  = 213524480ull;
    if (ws_size < WS_NEED) return;

    char* ws = (char*)d_ws;
    float* sum1   = (float*)(ws + 0);
    float* sumsq1 = (float*)(ws + 1024);
    float* sum2   = (float*)(ws + 2048);
    float* sumsq2 = (float*)(ws + 3072);
    u16*   y     = (u16*)(ws + OFF_Y);
    u16*   w2r   = (u16*)(ws + OFF_W2R);
    float* z_raw = (float*)(ws + OFF_Z);
    float* s0g   = (float*)(ws + OFF_S0);
    float* Wt2   = (float*)(ws + OFF_WT);
    u16*   u_hat = (u16*)(ws + OFF_UHAT);

    hipMemsetAsync(ws, 0, 4096, stream);               // BN sums (must precede prep's atomics)

    hipLaunchKernelGGL(prep_kernel, dim3(27328), dim3(256), 0, stream,
                       x, w1, b1, y, sum1, sumsq1, w2, w2r, W, Wt2, s0g);
    hipLaunchKernelGGL(conv2_mfma_kernel, dim3(512), dim3(256), 0, stream,
                       y, w2r, b2, sum1, sumsq1, g1, be1, z_raw, sum2, sumsq2);
    hipLaunchKernelGGL(uhat_kernel,   dim3(512),   dim3(256), 0, stream,
                       z_raw, sum2, sumsq2, g2, be2, Wt2, u_hat, s0g);
    hipLaunchKernelGGL(routing_kernel, dim3(512),  dim3(384), 0, stream,
                       u_hat, s0g, out);
}

// Round 24
// 939.648 us; speedup vs baseline: 1.0341x; 1.0341x over previous
//
#include <hip/hip_runtime.h>

typedef unsigned short u16;
typedef unsigned int   u32;
typedef __attribute__((ext_vector_type(8))) short bf16x8;  // 8 bf16 (4 VGPRs)
typedef __attribute__((ext_vector_type(4))) float f32x4;   // 4 fp32

// ---------- bf16 helpers (manual, RNE) ----------
__device__ __forceinline__ float bf2f(u16 u) { return __uint_as_float(((u32)u) << 16); }
__device__ __forceinline__ float bflo(u32 u) { return __uint_as_float(u << 16); }
__device__ __forceinline__ float bfhi(u32 u) { return __uint_as_float(u & 0xffff0000u); }
__device__ __forceinline__ u16 f2bf(float f) {
    u32 x = __float_as_uint(f);
    x += 0x7fffu + ((x >> 16) & 1u);   // round-to-nearest-even
    return (u16)(x >> 16);
}
// BN1+ReLU on a packed bf16 pair -- bit-identical to the old bnpack_kernel
__device__ __forceinline__ u32 bnpair(u32 v, float s0, float s1, float h0, float h1) {
    float a = fmaxf(0.f, fmaf(s0, bflo(v), h0));
    float c = fmaxf(0.f, fmaf(s1, bfhi(v), h1));
    return (u32)f2bf(a) | ((u32)f2bf(c) << 16);
}
// ---------- fp16 helpers (hardware cvt, RNE) ----------
__device__ __forceinline__ u16 f2h(float f) {
    _Float16 h = (_Float16)f;
    return __builtin_bit_cast(u16, h);
}
__device__ __forceinline__ float h2f(u16 u) {
    return (float)__builtin_bit_cast(_Float16, u);
}

// ---------- prep: conv1 + BOTH repacks + s0g zero in ONE dispatch ----------
// blocks 0..511      : conv1 (9x9 s1) + bias + bf16 store + BN1 stats (long pole, first)
// blocks 512..21247  : w2r[kk][ccc][co][cil] bf16 repack (5,308,416 elems)
// blocks 21248..27007: Wt2[i][je][d] f32 repack (1,474,560 elems)
// blocks 27008..27327: zero s0g (first touched by uhat, 2 dispatches later)
__global__ __launch_bounds__(256) void prep_kernel(const float* __restrict__ x,
                                                   const float* __restrict__ w1,
                                                   const float* __restrict__ b1,
                                                   u16* __restrict__ y,
                                                   float* __restrict__ sum1,
                                                   float* __restrict__ sumsq1,
                                                   const float* __restrict__ w2,
                                                   u16* __restrict__ w2r,
                                                   const float* __restrict__ W,
                                                   float* __restrict__ Wt2,
                                                   float* __restrict__ s0g) {
    __shared__ float xs[784];
    const int blk = blockIdx.x;
    const int t = threadIdx.x;
    if (blk < 512) {
        // ---- conv1, image b = blk ----
        const int b = blk;
        const float* xb = x + (size_t)b * 784;
        for (int idx = t; idx < 784; idx += 256) xs[idx] = xb[idx];
        float w[81];
#pragma unroll
        for (int q = 0; q < 81; ++q) w[q] = w1[(size_t)t * 81 + q];
        const float bias = b1[t];
        __syncthreads();

        float sl = 0.f, ssl = 0.f;
        u16* yb = y + (size_t)b * 400 * 256 + t;   // channels-last, stride 256
        for (int oh = 0; oh < 20; ++oh) {
            float acc[20];
#pragma unroll
            for (int ow = 0; ow < 20; ++ow) acc[ow] = bias;
#pragma unroll
            for (int kh = 0; kh < 9; ++kh) {
                const float4* rp = (const float4*)(&xs[(oh + kh) * 28]);
                float r[28];
#pragma unroll
                for (int k4 = 0; k4 < 7; ++k4) {
                    float4 f = rp[k4];
                    r[k4 * 4 + 0] = f.x; r[k4 * 4 + 1] = f.y;
                    r[k4 * 4 + 2] = f.z; r[k4 * 4 + 3] = f.w;
                }
#pragma unroll
                for (int kw = 0; kw < 9; ++kw) {
                    const float wv = w[kh * 9 + kw];
#pragma unroll
                    for (int ow = 0; ow < 20; ++ow)
                        acc[ow] = fmaf(wv, r[ow + kw], acc[ow]);
                }
            }
#pragma unroll
            for (int ow = 0; ow < 20; ++ow) {
                u16 q = f2bf(acc[ow]);
                float rv = bf2f(q);
                sl += rv; ssl += rv * rv;
                yb[(size_t)(oh * 20 + ow) * 256] = q;
            }
        }
        atomicAdd(&sum1[t], sl);
        atomicAdd(&sumsq1[t], ssl);
    } else if (blk < 21248) {
        // ---- w2r repack ----
        int idx = (blk - 512) * 256 + t;
        int cil = idx & 31;
        int co  = (idx >> 5) & 255;
        int ccc = (idx >> 13) & 7;
        int kk  = idx >> 16;
        int ci  = ccc * 32 + cil;
        w2r[idx] = f2bf(w2[(size_t)co * 20736 + (size_t)ci * 81 + kk]);
    } else if (blk < 27008) {
        // ---- Wt2 repack ----
        int idx = (blk - 21248) * 256 + t;
        int d  = idx & 7;
        int je = (idx >> 3) % 160;
        int i  = idx / 1280;
        int j = je >> 4, e = je & 15;
        Wt2[idx] = W[(((size_t)j * 1152 + i) * 8 + d) * 16 + e];
    } else {
        // ---- s0g zero (81,920 floats = 320 blocks x 256) ----
        s0g[(blk - 27008) * 256 + t] = 0.f;
    }
}

// ---------- conv2: implicit-im2col bf16 MFMA, kh-UNION staging + fused BN1 ----------
// FINAL measured-best configuration (session 1222 -> ~929 us; three samples
// 927.3/930.2/931.6):
//   round-3 pipeline structure (transient staging, 2 barriers/stage,
//   depth-3 A-frag / depth-2 B-frag register pipeline)
// + r12 BN1/ReLU staging fusion (bit-identical to the deleted bnpack pass)
// + r14 inline finalize_bn1 (per-stage BN consts from stats; rides in slack)
// + r20 T5 s_setprio around MFMA bursts (429->411 us; 2 independent
//   blocks/CU at uncorrelated phases = the m191 firing case)
// + r21 XCD co-partition decode (411->402 us, 5-sample A/B)
// __launch_bounds__(256,2) is REQUIRED: r23 A/B'd (256,1) -- spill vanished
// but the schedule regressed (409->438 us, MfmaUtil 27.5->25.6). The ~2 MB
// spill is part of the globally better schedule. Pad-136 rows (pad-140
// A/B'd: conflicts 2.7x worse). Remaining gap to the 126 us MFMA floor is
// the hipcc barrier-drain structural constraint -- 6 restructurings all
// regressed 5-60%.
__global__ __launch_bounds__(256, 2) void conv2_mfma_kernel(const u16* __restrict__ y,
                                                            const u16* __restrict__ w2r,
                                                            const float* __restrict__ b2,
                                                            const float* __restrict__ sum1,
                                                            const float* __restrict__ sumsq1,
                                                            const float* __restrict__ g1,
                                                            const float* __restrict__ be1,
                                                            float* __restrict__ z_raw,
                                                            float* __restrict__ sum2,
                                                            float* __restrict__ sumsq2) {
    __shared__ __align__(16) u16 stg[240 * 136];   // 65,280 B (pad-136: measured best)
    const int blk = blockIdx.x;
    const int cb = ((blk & 7) >> 2) * 128;         // XCD co-partition
    const int g  = ((blk >> 3) << 2) | (blk & 3);  // image pair, bijective per cb
    const int b0 = g * 2;
    const int t = threadIdx.x;
    const int wave = t >> 6, lane = t & 63;
    const int n16 = lane & 15, quad = lane >> 4;
    const int img = wave & 1, c64 = wave >> 1;     // wave: image, 64-co half of slice

    f32x4 zero = {0.f, 0.f, 0.f, 0.f};
    f32x4 acc[4][3];
#pragma unroll
    for (int ct = 0; ct < 4; ++ct)
#pragma unroll
        for (int pt = 0; pt < 3; ++pt) acc[ct][pt] = zero;

    // per-lane B-row bases (clamped: pos>=36 lanes read pos=35's valid data;
    // their acc is garbage but never stored -- epilogue guards pos<36)
    int brow[3];
#pragma unroll
    for (int pt = 0; pt < 3; ++pt) {
        int pos = pt * 16 + n16; if (pos > 35) pos = 35;
        const int oh = (pos * 43) >> 8;            // pos/6
        const int ow = pos - oh * 6;
        brow[pt] = (img * 6 + oh) * 20 + 2 * ow;   // + kw at use site
    }

    const int laneoff = (cb + c64 * 64 + n16) * 32 + quad * 8;   // weight lane offset
    const int c16t = t & 15;                       // staging channel group (stage-invariant)

    bf16x8 abuf[3][4];   // depth-3 A-frag pipeline (48 VGPR, 3-itt live range)
    bf16x8 bbuf[2][3];   // depth-2 B-frag pipeline (24 VGPR, 2-itt live range)

    // itt = kw*4 + ccc, 0..35; base = w2r + kh*589824 + cp*32768 + laneoff
    auto loadA = [&](bf16x8 (&dst)[4], const u16* basep, int ittv) {
        const u16* wa = basep + (ittv >> 2) * 65536 + (ittv & 3) * 8192;
#pragma unroll
        for (int ct = 0; ct < 4; ++ct)
            dst[ct] = *((const bf16x8*)(wa + ct * 512));         // 16 co * 32 ci
    };
    auto loadB = [&](bf16x8 (&dst)[3], int ittv) {
        const int kw = ittv >> 2, ccc = ittv & 3;
#pragma unroll
        for (int pt = 0; pt < 3; ++pt)
            dst[pt] = *((const bf16x8*)(stg + (brow[pt] + kw) * 136
                                        + ccc * 32 + quad * 8));
    };

    // prologue: stage-0 A preloads (itt 0,1,2)
    {
        const u16* w0 = w2r + laneoff;             // kh=0, cp=0
        loadA(abuf[0], w0, 0);
        loadA(abuf[1], w0, 1);
        loadA(abuf[2], w0, 2);
    }

    for (int kh = 0; kh < 9; ++kh) {
        for (int cp = 0; cp < 2; ++cp) {
            __syncthreads();                       // prev compute done reading stg
            // transient staging + fused BN1/ReLU: 240 rows x 256 B, 15
            // uint4/thread; BN constants for this thread's 8 channels
            // computed inline from BN1 stats (transient, bit-identical to
            // the old finalize_bn kernel)
            {
                const int chb = cp * 128 + c16t * 8;
                float scv[8], shv[8];
#pragma unroll
                for (int cc = 0; cc < 8; ++cc) {
                    const float m   = sum1[chb + cc] * (1.f / 204800.f);
                    const float var = sumsq1[chb + cc] * (1.f / 204800.f) - m * m;
                    const float sc  = g1[chb + cc] * rsqrtf(var + 1e-5f);
                    scv[cc] = sc;
                    shv[cc] = be1[chb + cc] - m * sc;
                }
#pragma unroll
                for (int q = 0; q < 15; ++q) {
                    const int v = t + q * 256;     // < 3840
                    const int rI = v >> 4, c16 = v & 15;   // c16 == c16t
                    const int i2 = (rI >= 120) ? 1 : 0;
                    const int rr = rI - i2 * 120;
                    const int oh = rr / 20;
                    const int iw = rr - oh * 20;
                    const int ip = (2 * oh + kh) * 20 + iw;
                    uint4 d = *((const uint4*)(y + ((size_t)(b0 + i2) * 400 + ip) * 256
                                               + cp * 128 + c16 * 8));
                    d.x = bnpair(d.x, scv[0], scv[1], shv[0], shv[1]);
                    d.y = bnpair(d.y, scv[2], scv[3], shv[2], shv[3]);
                    d.z = bnpair(d.z, scv[4], scv[5], shv[4], shv[5]);
                    d.w = bnpair(d.w, scv[6], scv[7], shv[6], shv[7]);
                    *((uint4*)(stg + rI * 136 + c16 * 8)) = d;
                }
            }
            __syncthreads();

            const int khn = (cp == 1) ? kh + 1 : kh;   // next stage coords
            const int cpn = cp ^ 1;
            const u16* wbase = w2r + (size_t)kh * 589824 + (size_t)cp * 32768 + laneoff;
            const u16* wnext = w2r + (size_t)khn * 589824 + (size_t)cpn * 32768 + laneoff;

            loadB(bbuf[0], 0);                     // B preloads for itt 0,1
            loadB(bbuf[1], 1);

#pragma unroll
            for (int itt = 0; itt < 36; ++itt) {
                const int a_i = itt % 3, b_i = itt % 2;
                __builtin_amdgcn_s_setprio(1);     // T5: favor MFMA-issuing wave
#pragma unroll
                for (int ct = 0; ct < 4; ++ct)
#pragma unroll
                    for (int pt = 0; pt < 3; ++pt)
                        acc[ct][pt] = __builtin_amdgcn_mfma_f32_16x16x32_bf16(
                            abuf[a_i][ct], bbuf[b_i][pt], acc[ct][pt], 0, 0, 0);
                __builtin_amdgcn_s_setprio(0);
                // rotate: A prefetch distance 3 (tail wraps into next stage),
                // B prefetch distance 2 (LDS, stage-local)
                if (itt < 33) loadA(abuf[a_i], wbase, itt + 3);
                else          loadA(abuf[a_i], wnext, itt + 3 - 36);
                if (itt < 34) loadB(bbuf[b_i], itt + 2);
            }
        }
    }

    // epilogue: bias, store z[b0+img][co][36], BN2 stats
#pragma unroll
    for (int ct = 0; ct < 4; ++ct) {
#pragma unroll
        for (int r = 0; r < 4; ++r) {
            const int co = cb + c64 * 64 + ct * 16 + quad * 4 + r;
            const float bias = b2[co];
            float s = 0.f, ss = 0.f;
#pragma unroll
            for (int pt = 0; pt < 3; ++pt) {
                const int pos = pt * 16 + n16;
                if (pos < 36) {
                    float v = acc[ct][pt][r] + bias;
                    z_raw[((size_t)(b0 + img) * 256 + co) * 36 + pos] = v;
                    s += v; ss += v * v;
                }
            }
#pragma unroll
            for (int m = 1; m < 16; m <<= 1) {
                s  += __shfl_xor(s,  m, 64);
                ss += __shfl_xor(ss, m, 64);
            }
            if (n16 == 0) { atomicAdd(&sum2[co], s); atomicAdd(&sumsq2[co], ss); }
        }
    }
}

// ---------- u_hat: fused BN2+ReLU staging (ubuild + finalize_bn2 eliminated) ----------
// r13: stage directly from z_raw (index identity), BN2+ReLU inline, fp16
// quantization reproduced bit-identically via h2f(f2h(val)). r15: the
// block's 32 channels' (sc,sh) computed ONCE by threads 0-31 into a 256 B
// LDS table (bit-identical), staging reads via broadcast.
__global__ __launch_bounds__(256) void uhat_kernel(const float* __restrict__ z_raw,
                                                   const float* __restrict__ sum2,
                                                   const float* __restrict__ sumsq2,
                                                   const float* __restrict__ g2,
                                                   const float* __restrict__ be2,
                                                   const float* __restrict__ Wt2,
                                                   u16* __restrict__ u_hat,
                                                   float* __restrict__ s0g) {
    __shared__ float utl[8 * 8 * 144];    // [bb][d][ii], 36 KB
    __shared__ float scl[32], shl[32];    // BN2 consts for this block's channels
    const int bg = blockIdx.x >> 3;       // 64 image-groups of 8
    const int ic = blockIdx.x & 7;        // 8 i-chunks of 144
    const int b0 = bg * 8, i0 = ic * 144;
    if (threadIdx.x < 32) {
        const int d = threadIdx.x >> 2, j = threadIdx.x & 3;
        const int c = d * 32 + ic * 4 + j;
        const float m   = sum2[c] * (1.f / 18432.f);
        const float var = sumsq2[c] * (1.f / 18432.f) - m * m;
        const float sc  = g2[c] * rsqrtf(var + 1e-5f);
        scl[threadIdx.x] = sc;
        shl[threadIdx.x] = be2[c] - m * sc;
    }
    __syncthreads();
    for (int v = threadIdx.x; v < 8 * 8 * 144; v += 256) {
        int ii = v % 144; int d = (v / 144) & 7; int bb = v / 1152;
        const int li = d * 4 + ii / 36;   // LDS table index
        float z = z_raw[(size_t)(b0 + bb) * 9216 + d * 1152 + i0 + ii];
        float val = fmaxf(0.f, fmaf(scl[li], z, shl[li]));
        utl[v] = h2f(f2h(val));           // bit-identical to ubuild's fp16 round
    }
    __syncthreads();
    for (int q = 0; q < 90; ++q) {
        int o = q * 256 + threadIdx.x;    // 144*160 = 23040 = 90*256
        int ii = o / 160, je = o - ii * 160;
        const float* wp = Wt2 + ((size_t)(i0 + ii) * 160 + je) * 8;
        float w[8];
#pragma unroll
        for (int d = 0; d < 8; ++d) w[d] = wp[d];
#pragma unroll
        for (int bb = 0; bb < 8; ++bb) {
            float acc = 0.f;
#pragma unroll
            for (int d = 0; d < 8; ++d) acc = fmaf(w[d], utl[bb * 1152 + d * 144 + ii], acc);
            u_hat[(size_t)(b0 + bb) * 184320 + (size_t)(i0 + ii) * 160 + je] = f2h(acc);
        }
    }
    __syncthreads();   // drains stores (compiler emits vmcnt(0) before barrier)
    // s0 partials: 1280 (bb,je) pairs, 5 per thread; re-read own L2-hot tile
#pragma unroll
    for (int p = 0; p < 5; ++p) {
        const int pair = p * 256 + threadIdx.x;
        const int bb = pair / 160, je = pair - (pair / 160) * 160;
        const u16* up = u_hat + (size_t)(b0 + bb) * 184320 + (size_t)i0 * 160 + je;
        float s = 0.f;
        for (int ii = 0; ii < 144; ++ii) s += h2f(up[(size_t)ii * 160]);
        atomicAdd(&s0g[(size_t)(b0 + bb) * 160 + je], s);
    }
}

// ---------- fused routing, iterations 1..4 (iter-0 s precomputed), double-buffered ----------
// Round-9 form (in every session best since): b-logits in LDS (pad-11 rows,
// conflict-free), phase B 4-way split accumulators. Session evidence:
// 2-blocks/CU via <=80 KB LDS does not materialize (r16); register b-logits
// at 384 thr spill (r15/r17); global-read routing thrashes HBM (r17).
__global__ __launch_bounds__(384) void routing_kernel(const u16* __restrict__ u_hat,
                                                      const float* __restrict__ s0g,
                                                      float* __restrict__ out) {
    __shared__ __align__(16) u16 uhs[2][96 * 168]; // 2 x 31.5 KB, row pad 168
    __shared__ float cl[10 * 96];
    __shared__ float part[320];
    __shared__ float sv[160];
    __shared__ float bls[12 * 96 * 11];            // b-logits, padded rows of 11
    const int t = threadIdx.x;
    const int b = blockIdx.x;
    const u16* uh = u_hat + (size_t)b * 184320;
    const int hB = (t < 320) ? (t / 160) : 0;
    const int je = (t < 320) ? (t - hB * 160) : 0;
    const int jB = je >> 4;

    // issue chunk-0 loads, then v0 = squash(0.1 * s0)
    uint4 rg[5];
    {
        const u16* src = uh;
#pragma unroll
        for (int q = 0; q < 5; ++q) {
            int v = t + q * 384, r = v / 20, c16 = v - r * 20;
            rg[q] = *((const uint4*)(src + r * 160 + c16 * 8));
        }
    }
    // zero b-logit LDS (pads included)
    for (int v = t; v < 12 * 96 * 11; v += 384) bls[v] = 0.f;
    if (t < 160) sv[t] = 0.1f * s0g[(size_t)b * 160 + t];
    __syncthreads();
    if (t < 10) {
        float n2 = 0.f;
#pragma unroll
        for (int e2 = 0; e2 < 16; ++e2) { float xx = sv[t * 16 + e2]; n2 += xx * xx; }
        float n = sqrtf(n2);
        float f = n / (n2 + 1.f);
#pragma unroll
        for (int e2 = 0; e2 < 16; ++e2) sv[t * 16 + e2] *= f;
    }
    // write chunk 0 into buf 0
#pragma unroll
    for (int q = 0; q < 5; ++q) {
        int v = t + q * 384, r = v / 20, c16 = v - r * 20;
        *((uint4*)(&uhs[0][r * 168 + c16 * 8])) = rg[q];
    }

    for (int k = 1; k <= 4; ++k) {
        float b0a = 0.f, b1a = 0.f, b2a = 0.f, b3a = 0.f;   // split sacc
        for (int c = 0; c < 12; ++c) {
            const int p = c & 1;
            const bool last = (k == 4) && (c == 11);
            __syncthreads();               // buf[p] writes + sv/cl updates visible
            if (!last) {                   // issue next-chunk loads (wraps to 0 across k)
                const int nc = (c == 11) ? 0 : c + 1;
                const u16* src = uh + (size_t)nc * 15360;
#pragma unroll
                for (int q = 0; q < 5; ++q) {
                    int v = t + q * 384, r = v / 20, c16 = v - r * 20;
                    rg[q] = *((const uint4*)(src + r * 160 + c16 * 8));
                }
            }
            if (t < 96) {                  // phase A
                const u16* row = uhs[p] + t * 168;
                float* blrow = &bls[(c * 96 + t) * 11];
                float bj[10];
#pragma unroll
                for (int j = 0; j < 10; ++j) {
                    uint4 a = *((const uint4*)(row + j * 16));
                    uint4 bq = *((const uint4*)(row + j * 16 + 8));
                    const float* vv = &sv[j * 16];
                    float dj = h2f((u16)(a.x & 0xffff)) * vv[0]  + h2f((u16)(a.x >> 16)) * vv[1]
                             + h2f((u16)(a.y & 0xffff)) * vv[2]  + h2f((u16)(a.y >> 16)) * vv[3]
                             + h2f((u16)(a.z & 0xffff)) * vv[4]  + h2f((u16)(a.z >> 16)) * vv[5]
                             + h2f((u16)(a.w & 0xffff)) * vv[6]  + h2f((u16)(a.w >> 16)) * vv[7]
                             + h2f((u16)(bq.x & 0xffff)) * vv[8]  + h2f((u16)(bq.x >> 16)) * vv[9]
                             + h2f((u16)(bq.y & 0xffff)) * vv[10] + h2f((u16)(bq.y >> 16)) * vv[11]
                             + h2f((u16)(bq.z & 0xffff)) * vv[12] + h2f((u16)(bq.z >> 16)) * vv[13]
                             + h2f((u16)(bq.w & 0xffff)) * vv[14] + h2f((u16)(bq.w >> 16)) * vv[15];
                    float nb = blrow[j] + dj;
                    blrow[j] = nb;
                    bj[j] = nb;
                }
                float mx = bj[0];
#pragma unroll
                for (int j = 1; j < 10; ++j) mx = fmaxf(mx, bj[j]);
                float s = 0.f;
#pragma unroll
                for (int j = 0; j < 10; ++j) { bj[j] = __expf(bj[j] - mx); s += bj[j]; }
                float inv = 1.f / s;
#pragma unroll
                for (int j = 0; j < 10; ++j) cl[j * 96 + t] = bj[j] * inv;
            }
            __syncthreads();               // cl visible
            if (t < 320) {                 // phase B: 48 rows, 4-way split acc
                const int r0 = hB * 48;
                const float* clj = &cl[jB * 96 + r0];
                const u16* up = uhs[p] + r0 * 168 + je;
#pragma unroll 3
                for (int il = 0; il < 48; il += 4) {
                    b0a = fmaf(clj[il],     h2f(up[(il)     * 168]), b0a);
                    b1a = fmaf(clj[il + 1], h2f(up[(il + 1) * 168]), b1a);
                    b2a = fmaf(clj[il + 2], h2f(up[(il + 2) * 168]), b2a);
                    b3a = fmaf(clj[il + 3], h2f(up[(il + 3) * 168]), b3a);
                }
            }
            if (!last) {                   // write next chunk into the other buffer
#pragma unroll
                for (int q = 0; q < 5; ++q) {
                    int v = t + q * 384, r = v / 20, c16 = v - r * 20;
                    *((uint4*)(&uhs[p ^ 1][r * 168 + c16 * 8])) = rg[q];
                }
            }
        }
        __syncthreads();
        if (t < 320) part[t] = (b0a + b1a) + (b2a + b3a);
        __syncthreads();
        if (t < 160) sv[t] = part[t] + part[t + 160];
        __syncthreads();
        if (t < 10) {
            float n2 = 0.f;
#pragma unroll
            for (int e2 = 0; e2 < 16; ++e2) { float xx = sv[t * 16 + e2]; n2 += xx * xx; }
            float n = sqrtf(n2);
            float f = n / (n2 + 1.f);
#pragma unroll
            for (int e2 = 0; e2 < 16; ++e2) sv[t * 16 + e2] *= f;
        }
    }
    __syncthreads();
    if (t < 160) out[(size_t)b * 160 + t] = sv[t];
}

extern "C" void kernel_launch(void* const* d_in, const int* in_sizes, int n_in,
                              void* d_out, int out_size, void* d_ws, size_t ws_size,
                              hipStream_t stream) {
    const float* x   = (const float*)d_in[0];
    const float* w1  = (const float*)d_in[1];
    const float* b1  = (const float*)d_in[2];
    const float* g1  = (const float*)d_in[3];
    const float* be1 = (const float*)d_in[4];
    const float* w2  = (const float*)d_in[5];
    const float* b2  = (const float*)d_in[6];
    const float* g2  = (const float*)d_in[7];
    const float* be2 = (const float*)d_in[8];
    const float* W   = (const float*)d_in[9];
    float* out = (float*)d_out;

    // ---- workspace layout (peak 213,524,480 B == proven-safe bound) ----
    const size_t OFF_UHAT = 8192;                       // 188,743,680 B (fp16, full batch)
    const size_t OFF_Y    = 8192;                       // 104,857,600 B (in u_hat region)
    const size_t OFF_W2R  = 104865792ull;               //  10,616,832 B (in u_hat region)
    const size_t OFF_Z    = 126099456ull;               //  18,874,368 B (in u_hat region)
    const size_t OFF_S0   = 198189056ull;               //     327,680 B (s0)
    const size_t OFF_WT   = 207626240ull;               //   5,898,240 B
    const size_t WS_NEED  = 213524480ull;
    if (ws_size < WS_NEED) return;

    char* ws = (char*)d_ws;
    float* sum1   = (float*)(ws + 0);
    float* sumsq1 = (float*)(ws + 1024);
    float* sum2   = (float*)(ws + 2048);
    float* sumsq2 = (float*)(ws + 3072);
    u16*   y     = (u16*)(ws + OFF_Y);
    u16*   w2r   = (u16*)(ws + OFF_W2R);
    float* z_raw = (float*)(ws + OFF_Z);
    float* s0g   = (float*)(ws + OFF_S0);
    float* Wt2   = (float*)(ws + OFF_WT);
    u16*   u_hat = (u16*)(ws + OFF_UHAT);

    hipMemsetAsync(ws, 0, 4096, stream);               // BN sums (must precede prep's atomics)

    hipLaunchKernelGGL(prep_kernel, dim3(27328), dim3(256), 0, stream,
                       x, w1, b1, y, sum1, sumsq1, w2, w2r, W, Wt2, s0g);
    hipLaunchKernelGGL(conv2_mfma_kernel, dim3(512), dim3(256), 0, stream,
                       y, w2r, b2, sum1, sumsq1, g1, be1, z_raw, sum2, sumsq2);
    hipLaunchKernelGGL(uhat_kernel,   dim3(512),   dim3(256), 0, stream,
                       z_raw, sum2, sumsq2, g2, be2, Wt2, u_hat, s0g);
    hipLaunchKernelGGL(routing_kernel, dim3(512),  dim3(384), 0, stream,
                       u_hat, s0g, out);
}

// Round 25
// 896.269 us; speedup vs baseline: 1.0841x; 1.0484x over previous
//
#include <hip/hip_runtime.h>

typedef unsigned short u16;
typedef unsigned int   u32;
typedef __attribute__((ext_vector_type(8))) short bf16x8;  // 8 bf16 (4 VGPRs)
typedef __attribute__((ext_vector_type(4))) float f32x4;   // 4 fp32

// ---------- bf16 helpers (manual, RNE) ----------
__device__ __forceinline__ float bf2f(u16 u) { return __uint_as_float(((u32)u) << 16); }
__device__ __forceinline__ float bflo(u32 u) { return __uint_as_float(u << 16); }
__device__ __forceinline__ float bfhi(u32 u) { return __uint_as_float(u & 0xffff0000u); }
__device__ __forceinline__ u16 f2bf(float f) {
    u32 x = __float_as_uint(f);
    x += 0x7fffu + ((x >> 16) & 1u);   // round-to-nearest-even
    return (u16)(x >> 16);
}
// BN1+ReLU on a packed bf16 pair -- bit-identical to the old bnpack_kernel
__device__ __forceinline__ u32 bnpair(u32 v, float s0, float s1, float h0, float h1) {
    float a = fmaxf(0.f, fmaf(s0, bflo(v), h0));
    float c = fmaxf(0.f, fmaf(s1, bfhi(v), h1));
    return (u32)f2bf(a) | ((u32)f2bf(c) << 16);
}
// ---------- fp16 helpers (hardware cvt, RNE) ----------
__device__ __forceinline__ u16 f2h(float f) {
    _Float16 h = (_Float16)f;
    return __builtin_bit_cast(u16, h);
}
__device__ __forceinline__ float h2f(u16 u) {
    return (float)__builtin_bit_cast(_Float16, u);
}

// ---------- prep: conv1 + BOTH repacks + s0g zero in ONE dispatch ----------
// blocks 0..511      : conv1 (9x9 s1) + bias + bf16 store + BN1 stats (long pole, first)
// blocks 512..21247  : w2r[kk][ccc][co][cil] bf16 repack (5,308,416 elems)
// blocks 21248..27007: Wt2[i][je][d] f32 repack (1,474,560 elems)
// blocks 27008..27327: zero s0g (first touched by uhat, 2 dispatches later)
__global__ __launch_bounds__(256) void prep_kernel(const float* __restrict__ x,
                                                   const float* __restrict__ w1,
                                                   const float* __restrict__ b1,
                                                   u16* __restrict__ y,
                                                   float* __restrict__ sum1,
                                                   float* __restrict__ sumsq1,
                                                   const float* __restrict__ w2,
                                                   u16* __restrict__ w2r,
                                                   const float* __restrict__ W,
                                                   float* __restrict__ Wt2,
                                                   float* __restrict__ s0g) {
    __shared__ float xs[784];
    const int blk = blockIdx.x;
    const int t = threadIdx.x;
    if (blk < 512) {
        // ---- conv1, image b = blk ----
        const int b = blk;
        const float* xb = x + (size_t)b * 784;
        for (int idx = t; idx < 784; idx += 256) xs[idx] = xb[idx];
        float w[81];
#pragma unroll
        for (int q = 0; q < 81; ++q) w[q] = w1[(size_t)t * 81 + q];
        const float bias = b1[t];
        __syncthreads();

        float sl = 0.f, ssl = 0.f;
        u16* yb = y + (size_t)b * 400 * 256 + t;   // channels-last, stride 256
        for (int oh = 0; oh < 20; ++oh) {
            float acc[20];
#pragma unroll
            for (int ow = 0; ow < 20; ++ow) acc[ow] = bias;
#pragma unroll
            for (int kh = 0; kh < 9; ++kh) {
                const float4* rp = (const float4*)(&xs[(oh + kh) * 28]);
                float r[28];
#pragma unroll
                for (int k4 = 0; k4 < 7; ++k4) {
                    float4 f = rp[k4];
                    r[k4 * 4 + 0] = f.x; r[k4 * 4 + 1] = f.y;
                    r[k4 * 4 + 2] = f.z; r[k4 * 4 + 3] = f.w;
                }
#pragma unroll
                for (int kw = 0; kw < 9; ++kw) {
                    const float wv = w[kh * 9 + kw];
#pragma unroll
                    for (int ow = 0; ow < 20; ++ow)
                        acc[ow] = fmaf(wv, r[ow + kw], acc[ow]);
                }
            }
#pragma unroll
            for (int ow = 0; ow < 20; ++ow) {
                u16 q = f2bf(acc[ow]);
                float rv = bf2f(q);
                sl += rv; ssl += rv * rv;
                yb[(size_t)(oh * 20 + ow) * 256] = q;
            }
        }
        atomicAdd(&sum1[t], sl);
        atomicAdd(&sumsq1[t], ssl);
    } else if (blk < 21248) {
        // ---- w2r repack ----
        int idx = (blk - 512) * 256 + t;
        int cil = idx & 31;
        int co  = (idx >> 5) & 255;
        int ccc = (idx >> 13) & 7;
        int kk  = idx >> 16;
        int ci  = ccc * 32 + cil;
        w2r[idx] = f2bf(w2[(size_t)co * 20736 + (size_t)ci * 81 + kk]);
    } else if (blk < 27008) {
        // ---- Wt2 repack ----
        int idx = (blk - 21248) * 256 + t;
        int d  = idx & 7;
        int je = (idx >> 3) % 160;
        int i  = idx / 1280;
        int j = je >> 4, e = je & 15;
        Wt2[idx] = W[(((size_t)j * 1152 + i) * 8 + d) * 16 + e];
    } else {
        // ---- s0g zero (81,920 floats = 320 blocks x 256) ----
        s0g[(blk - 27008) * 256 + t] = 0.f;
    }
}

// ---------- conv2: implicit-im2col bf16 MFMA, kh-UNION staging + fused BN1 ----------
// FINAL measured-best configuration (confirmed r20/r21/r22/r24):
//   round-3 pipeline + r12 BN1/ReLU staging fusion + r14 inline finalize_bn1
// + r20 T5 s_setprio around MFMA bursts + r21 XCD co-partition decode.
// __launch_bounds__(256,2) REQUIRED (r23 A/B: (256,1) regressed 409->438).
// Pad-136 rows (pad-140 A/B'd worse). Remaining gap to the 126 us MFMA
// floor is the hipcc barrier-drain structural constraint.
__global__ __launch_bounds__(256, 2) void conv2_mfma_kernel(const u16* __restrict__ y,
                                                            const u16* __restrict__ w2r,
                                                            const float* __restrict__ b2,
                                                            const float* __restrict__ sum1,
                                                            const float* __restrict__ sumsq1,
                                                            const float* __restrict__ g1,
                                                            const float* __restrict__ be1,
                                                            float* __restrict__ z_raw,
                                                            float* __restrict__ sum2,
                                                            float* __restrict__ sumsq2) {
    __shared__ __align__(16) u16 stg[240 * 136];   // 65,280 B (pad-136: measured best)
    const int blk = blockIdx.x;
    const int cb = ((blk & 7) >> 2) * 128;         // XCD co-partition
    const int g  = ((blk >> 3) << 2) | (blk & 3);  // image pair, bijective per cb
    const int b0 = g * 2;
    const int t = threadIdx.x;
    const int wave = t >> 6, lane = t & 63;
    const int n16 = lane & 15, quad = lane >> 4;
    const int img = wave & 1, c64 = wave >> 1;     // wave: image, 64-co half of slice

    f32x4 zero = {0.f, 0.f, 0.f, 0.f};
    f32x4 acc[4][3];
#pragma unroll
    for (int ct = 0; ct < 4; ++ct)
#pragma unroll
        for (int pt = 0; pt < 3; ++pt) acc[ct][pt] = zero;

    // per-lane B-row bases (clamped: pos>=36 lanes read pos=35's valid data;
    // their acc is garbage but never stored -- epilogue guards pos<36)
    int brow[3];
#pragma unroll
    for (int pt = 0; pt < 3; ++pt) {
        int pos = pt * 16 + n16; if (pos > 35) pos = 35;
        const int oh = (pos * 43) >> 8;            // pos/6
        const int ow = pos - oh * 6;
        brow[pt] = (img * 6 + oh) * 20 + 2 * ow;   // + kw at use site
    }

    const int laneoff = (cb + c64 * 64 + n16) * 32 + quad * 8;   // weight lane offset
    const int c16t = t & 15;                       // staging channel group (stage-invariant)

    bf16x8 abuf[3][4];   // depth-3 A-frag pipeline (48 VGPR, 3-itt live range)
    bf16x8 bbuf[2][3];   // depth-2 B-frag pipeline (24 VGPR, 2-itt live range)

    // itt = kw*4 + ccc, 0..35; base = w2r + kh*589824 + cp*32768 + laneoff
    auto loadA = [&](bf16x8 (&dst)[4], const u16* basep, int ittv) {
        const u16* wa = basep + (ittv >> 2) * 65536 + (ittv & 3) * 8192;
#pragma unroll
        for (int ct = 0; ct < 4; ++ct)
            dst[ct] = *((const bf16x8*)(wa + ct * 512));         // 16 co * 32 ci
    };
    auto loadB = [&](bf16x8 (&dst)[3], int ittv) {
        const int kw = ittv >> 2, ccc = ittv & 3;
#pragma unroll
        for (int pt = 0; pt < 3; ++pt)
            dst[pt] = *((const bf16x8*)(stg + (brow[pt] + kw) * 136
                                        + ccc * 32 + quad * 8));
    };

    // prologue: stage-0 A preloads (itt 0,1,2)
    {
        const u16* w0 = w2r + laneoff;             // kh=0, cp=0
        loadA(abuf[0], w0, 0);
        loadA(abuf[1], w0, 1);
        loadA(abuf[2], w0, 2);
    }

    for (int kh = 0; kh < 9; ++kh) {
        for (int cp = 0; cp < 2; ++cp) {
            __syncthreads();                       // prev compute done reading stg
            // transient staging + fused BN1/ReLU: 240 rows x 256 B, 15
            // uint4/thread; BN constants for this thread's 8 channels
            // computed inline from BN1 stats (transient, bit-identical to
            // the old finalize_bn kernel)
            {
                const int chb = cp * 128 + c16t * 8;
                float scv[8], shv[8];
#pragma unroll
                for (int cc = 0; cc < 8; ++cc) {
                    const float m   = sum1[chb + cc] * (1.f / 204800.f);
                    const float var = sumsq1[chb + cc] * (1.f / 204800.f) - m * m;
                    const float sc  = g1[chb + cc] * rsqrtf(var + 1e-5f);
                    scv[cc] = sc;
                    shv[cc] = be1[chb + cc] - m * sc;
                }
#pragma unroll
                for (int q = 0; q < 15; ++q) {
                    const int v = t + q * 256;     // < 3840
                    const int rI = v >> 4, c16 = v & 15;   // c16 == c16t
                    const int i2 = (rI >= 120) ? 1 : 0;
                    const int rr = rI - i2 * 120;
                    const int oh = rr / 20;
                    const int iw = rr - oh * 20;
                    const int ip = (2 * oh + kh) * 20 + iw;
                    uint4 d = *((const uint4*)(y + ((size_t)(b0 + i2) * 400 + ip) * 256
                                               + cp * 128 + c16 * 8));
                    d.x = bnpair(d.x, scv[0], scv[1], shv[0], shv[1]);
                    d.y = bnpair(d.y, scv[2], scv[3], shv[2], shv[3]);
                    d.z = bnpair(d.z, scv[4], scv[5], shv[4], shv[5]);
                    d.w = bnpair(d.w, scv[6], scv[7], shv[6], shv[7]);
                    *((uint4*)(stg + rI * 136 + c16 * 8)) = d;
                }
            }
            __syncthreads();

            const int khn = (cp == 1) ? kh + 1 : kh;   // next stage coords
            const int cpn = cp ^ 1;
            const u16* wbase = w2r + (size_t)kh * 589824 + (size_t)cp * 32768 + laneoff;
            const u16* wnext = w2r + (size_t)khn * 589824 + (size_t)cpn * 32768 + laneoff;

            loadB(bbuf[0], 0);                     // B preloads for itt 0,1
            loadB(bbuf[1], 1);

#pragma unroll
            for (int itt = 0; itt < 36; ++itt) {
                const int a_i = itt % 3, b_i = itt % 2;
                __builtin_amdgcn_s_setprio(1);     // T5: favor MFMA-issuing wave
#pragma unroll
                for (int ct = 0; ct < 4; ++ct)
#pragma unroll
                    for (int pt = 0; pt < 3; ++pt)
                        acc[ct][pt] = __builtin_amdgcn_mfma_f32_16x16x32_bf16(
                            abuf[a_i][ct], bbuf[b_i][pt], acc[ct][pt], 0, 0, 0);
                __builtin_amdgcn_s_setprio(0);
                // rotate: A prefetch distance 3 (tail wraps into next stage),
                // B prefetch distance 2 (LDS, stage-local)
                if (itt < 33) loadA(abuf[a_i], wbase, itt + 3);
                else          loadA(abuf[a_i], wnext, itt + 3 - 36);
                if (itt < 34) loadB(bbuf[b_i], itt + 2);
            }
        }
    }

    // epilogue: bias, store z[b0+img][co][36], BN2 stats
#pragma unroll
    for (int ct = 0; ct < 4; ++ct) {
#pragma unroll
        for (int r = 0; r < 4; ++r) {
            const int co = cb + c64 * 64 + ct * 16 + quad * 4 + r;
            const float bias = b2[co];
            float s = 0.f, ss = 0.f;
#pragma unroll
            for (int pt = 0; pt < 3; ++pt) {
                const int pos = pt * 16 + n16;
                if (pos < 36) {
                    float v = acc[ct][pt][r] + bias;
                    z_raw[((size_t)(b0 + img) * 256 + co) * 36 + pos] = v;
                    s += v; ss += v * v;
                }
            }
#pragma unroll
            for (int m = 1; m < 16; m <<= 1) {
                s  += __shfl_xor(s,  m, 64);
                ss += __shfl_xor(ss, m, 64);
            }
            if (n16 == 0) { atomicAdd(&sum2[co], s); atomicAdd(&sumsq2[co], ss); }
        }
    }
}

// ---------- u_hat: fused BN2+ReLU staging (ubuild + finalize_bn2 eliminated) ----------
// r13: stage directly from z_raw (index identity), BN2+ReLU inline, fp16
// quantization reproduced bit-identically via h2f(f2h(val)). r15: the
// block's 32 channels' (sc,sh) computed ONCE by threads 0-31 into a 256 B
// LDS table (bit-identical), staging reads via broadcast.
__global__ __launch_bounds__(256) void uhat_kernel(const float* __restrict__ z_raw,
                                                   const float* __restrict__ sum2,
                                                   const float* __restrict__ sumsq2,
                                                   const float* __restrict__ g2,
                                                   const float* __restrict__ be2,
                                                   const float* __restrict__ Wt2,
                                                   u16* __restrict__ u_hat,
                                                   float* __restrict__ s0g) {
    __shared__ float utl[8 * 8 * 144];    // [bb][d][ii], 36 KB
    __shared__ float scl[32], shl[32];    // BN2 consts for this block's channels
    const int bg = blockIdx.x >> 3;       // 64 image-groups of 8
    const int ic = blockIdx.x & 7;        // 8 i-chunks of 144
    const int b0 = bg * 8, i0 = ic * 144;
    if (threadIdx.x < 32) {
        const int d = threadIdx.x >> 2, j = threadIdx.x & 3;
        const int c = d * 32 + ic * 4 + j;
        const float m   = sum2[c] * (1.f / 18432.f);
        const float var = sumsq2[c] * (1.f / 18432.f) - m * m;
        const float sc  = g2[c] * rsqrtf(var + 1e-5f);
        scl[threadIdx.x] = sc;
        shl[threadIdx.x] = be2[c] - m * sc;
    }
    __syncthreads();
    for (int v = threadIdx.x; v < 8 * 8 * 144; v += 256) {
        int ii = v % 144; int d = (v / 144) & 7; int bb = v / 1152;
        const int li = d * 4 + ii / 36;   // LDS table index
        float z = z_raw[(size_t)(b0 + bb) * 9216 + d * 1152 + i0 + ii];
        float val = fmaxf(0.f, fmaf(scl[li], z, shl[li]));
        utl[v] = h2f(f2h(val));           // bit-identical to ubuild's fp16 round
    }
    __syncthreads();
    for (int q = 0; q < 90; ++q) {
        int o = q * 256 + threadIdx.x;    // 144*160 = 23040 = 90*256
        int ii = o / 160, je = o - ii * 160;
        const float* wp = Wt2 + ((size_t)(i0 + ii) * 160 + je) * 8;
        float w[8];
#pragma unroll
        for (int d = 0; d < 8; ++d) w[d] = wp[d];
#pragma unroll
        for (int bb = 0; bb < 8; ++bb) {
            float acc = 0.f;
#pragma unroll
            for (int d = 0; d < 8; ++d) acc = fmaf(w[d], utl[bb * 1152 + d * 144 + ii], acc);
            u_hat[(size_t)(b0 + bb) * 184320 + (size_t)(i0 + ii) * 160 + je] = f2h(acc);
        }
    }
    __syncthreads();   // drains stores (compiler emits vmcnt(0) before barrier)
    // s0 partials: 1280 (bb,je) pairs, 5 per thread; re-read own L2-hot tile
#pragma unroll
    for (int p = 0; p < 5; ++p) {
        const int pair = p * 256 + threadIdx.x;
        const int bb = pair / 160, je = pair - (pair / 160) * 160;
        const u16* up = u_hat + (size_t)(b0 + bb) * 184320 + (size_t)i0 * 160 + je;
        float s = 0.f;
        for (int ii = 0; ii < 144; ++ii) s += h2f(up[(size_t)ii * 160]);
        atomicAdd(&s0g[(size_t)(b0 + bb) * 160 + je], s);
    }
}

// ---------- fused routing, iterations 1..4 (iter-0 s precomputed), double-buffered ----------
// Round-9 base (b-logits in LDS pad-11, phase B 4-way split acc).
// r25 (this round): phase A WIDENED to all 384 threads -- previously only
// 96 of 384 threads worked through ~350 serial VALU ops per chunk (75% of
// the block idle at 1 block/CU; the m164-class serial-section signature).
// New mapping: thread t = 4r+s handles row r = t>>2, j-slice s = t&3
// (j in {s, s+4, s+8} ∩ [0,10) -- disjoint, covering). Row softmax reduces
// across the 4 CONSECUTIVE lanes via two __shfl_xor (no barrier). Max is
// exact; exp inputs identical; only sum-of-exps reassociates (few ulp,
// tolerance-proven). bls entries per (row,j) owned by exactly one thread.
__global__ __launch_bounds__(384) void routing_kernel(const u16* __restrict__ u_hat,
                                                      const float* __restrict__ s0g,
                                                      float* __restrict__ out) {
    __shared__ __align__(16) u16 uhs[2][96 * 168]; // 2 x 31.5 KB, row pad 168
    __shared__ float cl[10 * 96];
    __shared__ float part[320];
    __shared__ float sv[160];
    __shared__ float bls[12 * 96 * 11];            // b-logits, padded rows of 11
    const int t = threadIdx.x;
    const int b = blockIdx.x;
    const u16* uh = u_hat + (size_t)b * 184320;
    const int hB = (t < 320) ? (t / 160) : 0;
    const int je = (t < 320) ? (t - hB * 160) : 0;
    const int jB = je >> 4;
    const int rA = t >> 2, sA = t & 3;             // phase-A row / j-slice

    // issue chunk-0 loads, then v0 = squash(0.1 * s0)
    uint4 rg[5];
    {
        const u16* src = uh;
#pragma unroll
        for (int q = 0; q < 5; ++q) {
            int v = t + q * 384, r = v / 20, c16 = v - r * 20;
            rg[q] = *((const uint4*)(src + r * 160 + c16 * 8));
        }
    }
    // zero b-logit LDS (pads included)
    for (int v = t; v < 12 * 96 * 11; v += 384) bls[v] = 0.f;
    if (t < 160) sv[t] = 0.1f * s0g[(size_t)b * 160 + t];
    __syncthreads();
    if (t < 10) {
        float n2 = 0.f;
#pragma unroll
        for (int e2 = 0; e2 < 16; ++e2) { float xx = sv[t * 16 + e2]; n2 += xx * xx; }
        float n = sqrtf(n2);
        float f = n / (n2 + 1.f);
#pragma unroll
        for (int e2 = 0; e2 < 16; ++e2) sv[t * 16 + e2] *= f;
    }
    // write chunk 0 into buf 0
#pragma unroll
    for (int q = 0; q < 5; ++q) {
        int v = t + q * 384, r = v / 20, c16 = v - r * 20;
        *((uint4*)(&uhs[0][r * 168 + c16 * 8])) = rg[q];
    }

    for (int k = 1; k <= 4; ++k) {
        float b0a = 0.f, b1a = 0.f, b2a = 0.f, b3a = 0.f;   // split sacc
        for (int c = 0; c < 12; ++c) {
            const int p = c & 1;
            const bool last = (k == 4) && (c == 11);
            __syncthreads();               // buf[p] writes + sv/cl updates visible
            if (!last) {                   // issue next-chunk loads (wraps to 0 across k)
                const int nc = (c == 11) ? 0 : c + 1;
                const u16* src = uh + (size_t)nc * 15360;
#pragma unroll
                for (int q = 0; q < 5; ++q) {
                    int v = t + q * 384, r = v / 20, c16 = v - r * 20;
                    rg[q] = *((const uint4*)(src + r * 160 + c16 * 8));
                }
            }
            {                              // phase A: ALL 384 threads, 4 per row
                const u16* row = uhs[p] + rA * 168;
                float* blrow = &bls[(c * 96 + rA) * 11];
                float bj[3];
                float lmax = -1e30f;
#pragma unroll
                for (int u = 0; u < 3; ++u) {
                    const int j = sA + u * 4;
                    if (j < 10) {
                        uint4 a  = *((const uint4*)(row + j * 16));
                        uint4 bq = *((const uint4*)(row + j * 16 + 8));
                        const float* vv = &sv[j * 16];
                        float dj = h2f((u16)(a.x & 0xffff)) * vv[0]  + h2f((u16)(a.x >> 16)) * vv[1]
                                 + h2f((u16)(a.y & 0xffff)) * vv[2]  + h2f((u16)(a.y >> 16)) * vv[3]
                                 + h2f((u16)(a.z & 0xffff)) * vv[4]  + h2f((u16)(a.z >> 16)) * vv[5]
                                 + h2f((u16)(a.w & 0xffff)) * vv[6]  + h2f((u16)(a.w >> 16)) * vv[7]
                                 + h2f((u16)(bq.x & 0xffff)) * vv[8]  + h2f((u16)(bq.x >> 16)) * vv[9]
                                 + h2f((u16)(bq.y & 0xffff)) * vv[10] + h2f((u16)(bq.y >> 16)) * vv[11]
                                 + h2f((u16)(bq.z & 0xffff)) * vv[12] + h2f((u16)(bq.z >> 16)) * vv[13]
                                 + h2f((u16)(bq.w & 0xffff)) * vv[14] + h2f((u16)(bq.w >> 16)) * vv[15];
                        float nb = blrow[j] + dj;
                        blrow[j] = nb;
                        bj[u] = nb;
                        lmax = fmaxf(lmax, nb);
                    }
                }
                // row max across the 4 consecutive lanes (exact)
                lmax = fmaxf(lmax, __shfl_xor(lmax, 1, 64));
                lmax = fmaxf(lmax, __shfl_xor(lmax, 2, 64));
                float lsum = 0.f;
#pragma unroll
                for (int u = 0; u < 3; ++u) {
                    const int j = sA + u * 4;
                    if (j < 10) { bj[u] = __expf(bj[u] - lmax); lsum += bj[u]; }
                }
                lsum += __shfl_xor(lsum, 1, 64);
                lsum += __shfl_xor(lsum, 2, 64);
                const float inv = 1.f / lsum;
#pragma unroll
                for (int u = 0; u < 3; ++u) {
                    const int j = sA + u * 4;
                    if (j < 10) cl[j * 96 + rA] = bj[u] * inv;
                }
            }
            __syncthreads();               // cl visible
            if (t < 320) {                 // phase B: 48 rows, 4-way split acc
                const int r0 = hB * 48;
                const float* clj = &cl[jB * 96 + r0];
                const u16* up = uhs[p] + r0 * 168 + je;
#pragma unroll 3
                for (int il = 0; il < 48; il += 4) {
                    b0a = fmaf(clj[il],     h2f(up[(il)     * 168]), b0a);
                    b1a = fmaf(clj[il + 1], h2f(up[(il + 1) * 168]), b1a);
                    b2a = fmaf(clj[il + 2], h2f(up[(il + 2) * 168]), b2a);
                    b3a = fmaf(clj[il + 3], h2f(up[(il + 3) * 168]), b3a);
                }
            }
            if (!last) {                   // write next chunk into the other buffer
#pragma unroll
                for (int q = 0; q < 5; ++q) {
                    int v = t + q * 384, r = v / 20, c16 = v - r * 20;
                    *((uint4*)(&uhs[p ^ 1][r * 168 + c16 * 8])) = rg[q];
                }
            }
        }
        __syncthreads();
        if (t < 320) part[t] = (b0a + b1a) + (b2a + b3a);
        __syncthreads();
        if (t < 160) sv[t] = part[t] + part[t + 160];
        __syncthreads();
        if (t < 10) {
            float n2 = 0.f;
#pragma unroll
            for (int e2 = 0; e2 < 16; ++e2) { float xx = sv[t * 16 + e2]; n2 += xx * xx; }
            float n = sqrtf(n2);
            float f = n / (n2 + 1.f);
#pragma unroll
            for (int e2 = 0; e2 < 16; ++e2) sv[t * 16 + e2] *= f;
        }
    }
    __syncthreads();
    if (t < 160) out[(size_t)b * 160 + t] = sv[t];
}

extern "C" void kernel_launch(void* const* d_in, const int* in_sizes, int n_in,
                              void* d_out, int out_size, void* d_ws, size_t ws_size,
                              hipStream_t stream) {
    const float* x   = (const float*)d_in[0];
    const float* w1  = (const float*)d_in[1];
    const float* b1  = (const float*)d_in[2];
    const float* g1  = (const float*)d_in[3];
    const float* be1 = (const float*)d_in[4];
    const float* w2  = (const float*)d_in[5];
    const float* b2  = (const float*)d_in[6];
    const float* g2  = (const float*)d_in[7];
    const float* be2 = (const float*)d_in[8];
    const float* W   = (const float*)d_in[9];
    float* out = (float*)d_out;

    // ---- workspace layout (peak 213,524,480 B == proven-safe bound) ----
    const size_t OFF_UHAT = 8192;                       // 188,743,680 B (fp16, full batch)
    const size_t OFF_Y    = 8192;                       // 104,857,600 B (in u_hat region)
    const size_t OFF_W2R  = 104865792ull;               //  10,616,832 B (in u_hat region)
    const size_t OFF_Z    = 126099456ull;               //  18,874,368 B (in u_hat region)
    const size_t OFF_S0   = 198189056ull;               //     327,680 B (s0)
    const size_t OFF_WT   = 207626240ull;               //   5,898,240 B
    const size_t WS_NEED  = 213524480ull;
    if (ws_size < WS_NEED) return;

    char* ws = (char*)d_ws;
    float* sum1   = (float*)(ws + 0);
    float* sumsq1 = (float*)(ws + 1024);
    float* sum2   = (float*)(ws + 2048);
    float* sumsq2 = (float*)(ws + 3072);
    u16*   y     = (u16*)(ws + OFF_Y);
    u16*   w2r   = (u16*)(ws + OFF_W2R);
    float* z_raw = (float*)(ws + OFF_Z);
    float* s0g   = (float*)(ws + OFF_S0);
    float* Wt2   = (float*)(ws + OFF_WT);
    u16*   u_hat = (u16*)(ws + OFF_UHAT);

    hipMemsetAsync(ws, 0, 4096, stream);               // BN sums (must precede prep's atomics)

    hipLaunchKernelGGL(prep_kernel, dim3(27328), dim3(256), 0, stream,
                       x, w1, b1, y, sum1, sumsq1, w2, w2r, W, Wt2, s0g);
    hipLaunchKernelGGL(conv2_mfma_kernel, dim3(512), dim3(256), 0, stream,
                       y, w2r, b2, sum1, sumsq1, g1, be1, z_raw, sum2, sumsq2);
    hipLaunchKernelGGL(uhat_kernel,   dim3(512),   dim3(256), 0, stream,
                       z_raw, sum2, sumsq2, g2, be2, Wt2, u_hat, s0g);
    hipLaunchKernelGGL(routing_kernel, dim3(512),  dim3(384), 0, stream,
                       u_hat, s0g, out);
}

// Round 26
// 882.836 us; speedup vs baseline: 1.1006x; 1.0152x over previous
//
#include <hip/hip_runtime.h>

typedef unsigned short u16;
typedef unsigned int   u32;
typedef __attribute__((ext_vector_type(8))) short bf16x8;  // 8 bf16 (4 VGPRs)
typedef __attribute__((ext_vector_type(4))) float f32x4;   // 4 fp32

// ---------- bf16 helpers (manual, RNE) ----------
__device__ __forceinline__ float bf2f(u16 u) { return __uint_as_float(((u32)u) << 16); }
__device__ __forceinline__ float bflo(u32 u) { return __uint_as_float(u << 16); }
__device__ __forceinline__ float bfhi(u32 u) { return __uint_as_float(u & 0xffff0000u); }
__device__ __forceinline__ u16 f2bf(float f) {
    u32 x = __float_as_uint(f);
    x += 0x7fffu + ((x >> 16) & 1u);   // round-to-nearest-even
    return (u16)(x >> 16);
}
// BN1+ReLU on a packed bf16 pair -- bit-identical to the old bnpack_kernel
__device__ __forceinline__ u32 bnpair(u32 v, float s0, float s1, float h0, float h1) {
    float a = fmaxf(0.f, fmaf(s0, bflo(v), h0));
    float c = fmaxf(0.f, fmaf(s1, bfhi(v), h1));
    return (u32)f2bf(a) | ((u32)f2bf(c) << 16);
}
// ---------- fp16 helpers (hardware cvt, RNE) ----------
__device__ __forceinline__ u16 f2h(float f) {
    _Float16 h = (_Float16)f;
    return __builtin_bit_cast(u16, h);
}
__device__ __forceinline__ float h2f(u16 u) {
    return (float)__builtin_bit_cast(_Float16, u);
}

// ---------- prep: conv1 + BOTH repacks + s0g zero in ONE dispatch ----------
// blocks 0..511      : conv1 (9x9 s1) + bias + bf16 store + BN1 stats (long pole, first)
// blocks 512..21247  : w2r[kk][ccc][co][cil] bf16 repack (5,308,416 elems)
// blocks 21248..27007: Wt2[i][je][d] f32 repack (1,474,560 elems)
// blocks 27008..27327: zero s0g (first touched by uhat, 2 dispatches later)
__global__ __launch_bounds__(256) void prep_kernel(const float* __restrict__ x,
                                                   const float* __restrict__ w1,
                                                   const float* __restrict__ b1,
                                                   u16* __restrict__ y,
                                                   float* __restrict__ sum1,
                                                   float* __restrict__ sumsq1,
                                                   const float* __restrict__ w2,
                                                   u16* __restrict__ w2r,
                                                   const float* __restrict__ W,
                                                   float* __restrict__ Wt2,
                                                   float* __restrict__ s0g) {
    __shared__ float xs[784];
    const int blk = blockIdx.x;
    const int t = threadIdx.x;
    if (blk < 512) {
        // ---- conv1, image b = blk ----
        const int b = blk;
        const float* xb = x + (size_t)b * 784;
        for (int idx = t; idx < 784; idx += 256) xs[idx] = xb[idx];
        float w[81];
#pragma unroll
        for (int q = 0; q < 81; ++q) w[q] = w1[(size_t)t * 81 + q];
        const float bias = b1[t];
        __syncthreads();

        float sl = 0.f, ssl = 0.f;
        u16* yb = y + (size_t)b * 400 * 256 + t;   // channels-last, stride 256
        for (int oh = 0; oh < 20; ++oh) {
            float acc[20];
#pragma unroll
            for (int ow = 0; ow < 20; ++ow) acc[ow] = bias;
#pragma unroll
            for (int kh = 0; kh < 9; ++kh) {
                const float4* rp = (const float4*)(&xs[(oh + kh) * 28]);
                float r[28];
#pragma unroll
                for (int k4 = 0; k4 < 7; ++k4) {
                    float4 f = rp[k4];
                    r[k4 * 4 + 0] = f.x; r[k4 * 4 + 1] = f.y;
                    r[k4 * 4 + 2] = f.z; r[k4 * 4 + 3] = f.w;
                }
#pragma unroll
                for (int kw = 0; kw < 9; ++kw) {
                    const float wv = w[kh * 9 + kw];
#pragma unroll
                    for (int ow = 0; ow < 20; ++ow)
                        acc[ow] = fmaf(wv, r[ow + kw], acc[ow]);
                }
            }
#pragma unroll
            for (int ow = 0; ow < 20; ++ow) {
                u16 q = f2bf(acc[ow]);
                float rv = bf2f(q);
                sl += rv; ssl += rv * rv;
                yb[(size_t)(oh * 20 + ow) * 256] = q;
            }
        }
        atomicAdd(&sum1[t], sl);
        atomicAdd(&sumsq1[t], ssl);
    } else if (blk < 21248) {
        // ---- w2r repack ----
        int idx = (blk - 512) * 256 + t;
        int cil = idx & 31;
        int co  = (idx >> 5) & 255;
        int ccc = (idx >> 13) & 7;
        int kk  = idx >> 16;
        int ci  = ccc * 32 + cil;
        w2r[idx] = f2bf(w2[(size_t)co * 20736 + (size_t)ci * 81 + kk]);
    } else if (blk < 27008) {
        // ---- Wt2 repack ----
        int idx = (blk - 21248) * 256 + t;
        int d  = idx & 7;
        int je = (idx >> 3) % 160;
        int i  = idx / 1280;
        int j = je >> 4, e = je & 15;
        Wt2[idx] = W[(((size_t)j * 1152 + i) * 8 + d) * 16 + e];
    } else {
        // ---- s0g zero (81,920 floats = 320 blocks x 256) ----
        s0g[(blk - 27008) * 256 + t] = 0.f;
    }
}

// ---------- conv2: implicit-im2col bf16 MFMA, kh-UNION staging + fused BN1 ----------
// FINAL measured-best configuration (confirmed r20/r21/r22/r24):
//   round-3 pipeline + r12 BN1/ReLU staging fusion + r14 inline finalize_bn1
// + r20 T5 s_setprio around MFMA bursts + r21 XCD co-partition decode.
// __launch_bounds__(256,2) REQUIRED (r23 A/B: (256,1) regressed 409->438).
// Pad-136 rows (pad-140 A/B'd worse). Remaining gap to the 126 us MFMA
// floor is the hipcc barrier-drain structural constraint.
__global__ __launch_bounds__(256, 2) void conv2_mfma_kernel(const u16* __restrict__ y,
                                                            const u16* __restrict__ w2r,
                                                            const float* __restrict__ b2,
                                                            const float* __restrict__ sum1,
                                                            const float* __restrict__ sumsq1,
                                                            const float* __restrict__ g1,
                                                            const float* __restrict__ be1,
                                                            float* __restrict__ z_raw,
                                                            float* __restrict__ sum2,
                                                            float* __restrict__ sumsq2) {
    __shared__ __align__(16) u16 stg[240 * 136];   // 65,280 B (pad-136: measured best)
    const int blk = blockIdx.x;
    const int cb = ((blk & 7) >> 2) * 128;         // XCD co-partition
    const int g  = ((blk >> 3) << 2) | (blk & 3);  // image pair, bijective per cb
    const int b0 = g * 2;
    const int t = threadIdx.x;
    const int wave = t >> 6, lane = t & 63;
    const int n16 = lane & 15, quad = lane >> 4;
    const int img = wave & 1, c64 = wave >> 1;     // wave: image, 64-co half of slice

    f32x4 zero = {0.f, 0.f, 0.f, 0.f};
    f32x4 acc[4][3];
#pragma unroll
    for (int ct = 0; ct < 4; ++ct)
#pragma unroll
        for (int pt = 0; pt < 3; ++pt) acc[ct][pt] = zero;

    // per-lane B-row bases (clamped: pos>=36 lanes read pos=35's valid data;
    // their acc is garbage but never stored -- epilogue guards pos<36)
    int brow[3];
#pragma unroll
    for (int pt = 0; pt < 3; ++pt) {
        int pos = pt * 16 + n16; if (pos > 35) pos = 35;
        const int oh = (pos * 43) >> 8;            // pos/6
        const int ow = pos - oh * 6;
        brow[pt] = (img * 6 + oh) * 20 + 2 * ow;   // + kw at use site
    }

    const int laneoff = (cb + c64 * 64 + n16) * 32 + quad * 8;   // weight lane offset
    const int c16t = t & 15;                       // staging channel group (stage-invariant)

    bf16x8 abuf[3][4];   // depth-3 A-frag pipeline (48 VGPR, 3-itt live range)
    bf16x8 bbuf[2][3];   // depth-2 B-frag pipeline (24 VGPR, 2-itt live range)

    // itt = kw*4 + ccc, 0..35; base = w2r + kh*589824 + cp*32768 + laneoff
    auto loadA = [&](bf16x8 (&dst)[4], const u16* basep, int ittv) {
        const u16* wa = basep + (ittv >> 2) * 65536 + (ittv & 3) * 8192;
#pragma unroll
        for (int ct = 0; ct < 4; ++ct)
            dst[ct] = *((const bf16x8*)(wa + ct * 512));         // 16 co * 32 ci
    };
    auto loadB = [&](bf16x8 (&dst)[3], int ittv) {
        const int kw = ittv >> 2, ccc = ittv & 3;
#pragma unroll
        for (int pt = 0; pt < 3; ++pt)
            dst[pt] = *((const bf16x8*)(stg + (brow[pt] + kw) * 136
                                        + ccc * 32 + quad * 8));
    };

    // prologue: stage-0 A preloads (itt 0,1,2)
    {
        const u16* w0 = w2r + laneoff;             // kh=0, cp=0
        loadA(abuf[0], w0, 0);
        loadA(abuf[1], w0, 1);
        loadA(abuf[2], w0, 2);
    }

    for (int kh = 0; kh < 9; ++kh) {
        for (int cp = 0; cp < 2; ++cp) {
            __syncthreads();                       // prev compute done reading stg
            // transient staging + fused BN1/ReLU: 240 rows x 256 B, 15
            // uint4/thread; BN constants for this thread's 8 channels
            // computed inline from BN1 stats (transient, bit-identical to
            // the old finalize_bn kernel)
            {
                const int chb = cp * 128 + c16t * 8;
                float scv[8], shv[8];
#pragma unroll
                for (int cc = 0; cc < 8; ++cc) {
                    const float m   = sum1[chb + cc] * (1.f / 204800.f);
                    const float var = sumsq1[chb + cc] * (1.f / 204800.f) - m * m;
                    const float sc  = g1[chb + cc] * rsqrtf(var + 1e-5f);
                    scv[cc] = sc;
                    shv[cc] = be1[chb + cc] - m * sc;
                }
#pragma unroll
                for (int q = 0; q < 15; ++q) {
                    const int v = t + q * 256;     // < 3840
                    const int rI = v >> 4, c16 = v & 15;   // c16 == c16t
                    const int i2 = (rI >= 120) ? 1 : 0;
                    const int rr = rI - i2 * 120;
                    const int oh = rr / 20;
                    const int iw = rr - oh * 20;
                    const int ip = (2 * oh + kh) * 20 + iw;
                    uint4 d = *((const uint4*)(y + ((size_t)(b0 + i2) * 400 + ip) * 256
                                               + cp * 128 + c16 * 8));
                    d.x = bnpair(d.x, scv[0], scv[1], shv[0], shv[1]);
                    d.y = bnpair(d.y, scv[2], scv[3], shv[2], shv[3]);
                    d.z = bnpair(d.z, scv[4], scv[5], shv[4], shv[5]);
                    d.w = bnpair(d.w, scv[6], scv[7], shv[6], shv[7]);
                    *((uint4*)(stg + rI * 136 + c16 * 8)) = d;
                }
            }
            __syncthreads();

            const int khn = (cp == 1) ? kh + 1 : kh;   // next stage coords
            const int cpn = cp ^ 1;
            const u16* wbase = w2r + (size_t)kh * 589824 + (size_t)cp * 32768 + laneoff;
            const u16* wnext = w2r + (size_t)khn * 589824 + (size_t)cpn * 32768 + laneoff;

            loadB(bbuf[0], 0);                     // B preloads for itt 0,1
            loadB(bbuf[1], 1);

#pragma unroll
            for (int itt = 0; itt < 36; ++itt) {
                const int a_i = itt % 3, b_i = itt % 2;
                __builtin_amdgcn_s_setprio(1);     // T5: favor MFMA-issuing wave
#pragma unroll
                for (int ct = 0; ct < 4; ++ct)
#pragma unroll
                    for (int pt = 0; pt < 3; ++pt)
                        acc[ct][pt] = __builtin_amdgcn_mfma_f32_16x16x32_bf16(
                            abuf[a_i][ct], bbuf[b_i][pt], acc[ct][pt], 0, 0, 0);
                __builtin_amdgcn_s_setprio(0);
                // rotate: A prefetch distance 3 (tail wraps into next stage),
                // B prefetch distance 2 (LDS, stage-local)
                if (itt < 33) loadA(abuf[a_i], wbase, itt + 3);
                else          loadA(abuf[a_i], wnext, itt + 3 - 36);
                if (itt < 34) loadB(bbuf[b_i], itt + 2);
            }
        }
    }

    // epilogue: bias, store z[b0+img][co][36], BN2 stats
#pragma unroll
    for (int ct = 0; ct < 4; ++ct) {
#pragma unroll
        for (int r = 0; r < 4; ++r) {
            const int co = cb + c64 * 64 + ct * 16 + quad * 4 + r;
            const float bias = b2[co];
            float s = 0.f, ss = 0.f;
#pragma unroll
            for (int pt = 0; pt < 3; ++pt) {
                const int pos = pt * 16 + n16;
                if (pos < 36) {
                    float v = acc[ct][pt][r] + bias;
                    z_raw[((size_t)(b0 + img) * 256 + co) * 36 + pos] = v;
                    s += v; ss += v * v;
                }
            }
#pragma unroll
            for (int m = 1; m < 16; m <<= 1) {
                s  += __shfl_xor(s,  m, 64);
                ss += __shfl_xor(ss, m, 64);
            }
            if (n16 == 0) { atomicAdd(&sum2[co], s); atomicAdd(&sumsq2[co], ss); }
        }
    }
}

// ---------- u_hat: fused BN2+ReLU staging (ubuild + finalize_bn2 eliminated) ----------
// r13: stage directly from z_raw (index identity), BN2+ReLU inline, fp16
// quantization reproduced bit-identically via h2f(f2h(val)). r15: the
// block's 32 channels' (sc,sh) computed ONCE by threads 0-31 into a 256 B
// LDS table (bit-identical), staging reads via broadcast.
__global__ __launch_bounds__(256) void uhat_kernel(const float* __restrict__ z_raw,
                                                   const float* __restrict__ sum2,
                                                   const float* __restrict__ sumsq2,
                                                   const float* __restrict__ g2,
                                                   const float* __restrict__ be2,
                                                   const float* __restrict__ Wt2,
                                                   u16* __restrict__ u_hat,
                                                   float* __restrict__ s0g) {
    __shared__ float utl[8 * 8 * 144];    // [bb][d][ii], 36 KB
    __shared__ float scl[32], shl[32];    // BN2 consts for this block's channels
    const int bg = blockIdx.x >> 3;       // 64 image-groups of 8
    const int ic = blockIdx.x & 7;        // 8 i-chunks of 144
    const int b0 = bg * 8, i0 = ic * 144;
    if (threadIdx.x < 32) {
        const int d = threadIdx.x >> 2, j = threadIdx.x & 3;
        const int c = d * 32 + ic * 4 + j;
        const float m   = sum2[c] * (1.f / 18432.f);
        const float var = sumsq2[c] * (1.f / 18432.f) - m * m;
        const float sc  = g2[c] * rsqrtf(var + 1e-5f);
        scl[threadIdx.x] = sc;
        shl[threadIdx.x] = be2[c] - m * sc;
    }
    __syncthreads();
    for (int v = threadIdx.x; v < 8 * 8 * 144; v += 256) {
        int ii = v % 144; int d = (v / 144) & 7; int bb = v / 1152;
        const int li = d * 4 + ii / 36;   // LDS table index
        float z = z_raw[(size_t)(b0 + bb) * 9216 + d * 1152 + i0 + ii];
        float val = fmaxf(0.f, fmaf(scl[li], z, shl[li]));
        utl[v] = h2f(f2h(val));           // bit-identical to ubuild's fp16 round
    }
    __syncthreads();
    for (int q = 0; q < 90; ++q) {
        int o = q * 256 + threadIdx.x;    // 144*160 = 23040 = 90*256
        int ii = o / 160, je = o - ii * 160;
        const float* wp = Wt2 + ((size_t)(i0 + ii) * 160 + je) * 8;
        float w[8];
#pragma unroll
        for (int d = 0; d < 8; ++d) w[d] = wp[d];
#pragma unroll
        for (int bb = 0; bb < 8; ++bb) {
            float acc = 0.f;
#pragma unroll
            for (int d = 0; d < 8; ++d) acc = fmaf(w[d], utl[bb * 1152 + d * 144 + ii], acc);
            u_hat[(size_t)(b0 + bb) * 184320 + (size_t)(i0 + ii) * 160 + je] = f2h(acc);
        }
    }
    __syncthreads();   // drains stores (compiler emits vmcnt(0) before barrier)
    // s0 partials: 1280 (bb,je) pairs, 5 per thread; re-read own L2-hot tile
#pragma unroll
    for (int p = 0; p < 5; ++p) {
        const int pair = p * 256 + threadIdx.x;
        const int bb = pair / 160, je = pair - (pair / 160) * 160;
        const u16* up = u_hat + (size_t)(b0 + bb) * 184320 + (size_t)i0 * 160 + je;
        float s = 0.f;
        for (int ii = 0; ii < 144; ++ii) s += h2f(up[(size_t)ii * 160]);
        atomicAdd(&s0g[(size_t)(b0 + bb) * 160 + je], s);
    }
}

// ---------- fused routing, iterations 1..4 (iter-0 s precomputed), double-buffered ----------
// r25 FINAL form: b-logits in LDS (pad-11), phase B 4-way split acc, and
// phase A widened to ALL 384 threads (4 per row: thread t=4r+s handles row
// r=t>>2, j-slice s=t&3, j in {s,s+4,s+8} ∩ [0,10); row softmax via two
// __shfl_xor across the 4 consecutive lanes). Measured: routing serial
// phase-A depth /4 -> session best 896.3 us (-31 vs prior best).
__global__ __launch_bounds__(384) void routing_kernel(const u16* __restrict__ u_hat,
                                                      const float* __restrict__ s0g,
                                                      float* __restrict__ out) {
    __shared__ __align__(16) u16 uhs[2][96 * 168]; // 2 x 31.5 KB, row pad 168
    __shared__ float cl[10 * 96];
    __shared__ float part[320];
    __shared__ float sv[160];
    __shared__ float bls[12 * 96 * 11];            // b-logits, padded rows of 11
    const int t = threadIdx.x;
    const int b = blockIdx.x;
    const u16* uh = u_hat + (size_t)b * 184320;
    const int hB = (t < 320) ? (t / 160) : 0;
    const int je = (t < 320) ? (t - hB * 160) : 0;
    const int jB = je >> 4;
    const int rA = t >> 2, sA = t & 3;             // phase-A row / j-slice

    // issue chunk-0 loads, then v0 = squash(0.1 * s0)
    uint4 rg[5];
    {
        const u16* src = uh;
#pragma unroll
        for (int q = 0; q < 5; ++q) {
            int v = t + q * 384, r = v / 20, c16 = v - r * 20;
            rg[q] = *((const uint4*)(src + r * 160 + c16 * 8));
        }
    }
    // zero b-logit LDS (pads included)
    for (int v = t; v < 12 * 96 * 11; v += 384) bls[v] = 0.f;
    if (t < 160) sv[t] = 0.1f * s0g[(size_t)b * 160 + t];
    __syncthreads();
    if (t < 10) {
        float n2 = 0.f;
#pragma unroll
        for (int e2 = 0; e2 < 16; ++e2) { float xx = sv[t * 16 + e2]; n2 += xx * xx; }
        float n = sqrtf(n2);
        float f = n / (n2 + 1.f);
#pragma unroll
        for (int e2 = 0; e2 < 16; ++e2) sv[t * 16 + e2] *= f;
    }
    // write chunk 0 into buf 0
#pragma unroll
    for (int q = 0; q < 5; ++q) {
        int v = t + q * 384, r = v / 20, c16 = v - r * 20;
        *((uint4*)(&uhs[0][r * 168 + c16 * 8])) = rg[q];
    }

    for (int k = 1; k <= 4; ++k) {
        float b0a = 0.f, b1a = 0.f, b2a = 0.f, b3a = 0.f;   // split sacc
        for (int c = 0; c < 12; ++c) {
            const int p = c & 1;
            const bool last = (k == 4) && (c == 11);
            __syncthreads();               // buf[p] writes + sv/cl updates visible
            if (!last) {                   // issue next-chunk loads (wraps to 0 across k)
                const int nc = (c == 11) ? 0 : c + 1;
                const u16* src = uh + (size_t)nc * 15360;
#pragma unroll
                for (int q = 0; q < 5; ++q) {
                    int v = t + q * 384, r = v / 20, c16 = v - r * 20;
                    rg[q] = *((const uint4*)(src + r * 160 + c16 * 8));
                }
            }
            {                              // phase A: ALL 384 threads, 4 per row
                const u16* row = uhs[p] + rA * 168;
                float* blrow = &bls[(c * 96 + rA) * 11];
                float bj[3];
                float lmax = -1e30f;
#pragma unroll
                for (int u = 0; u < 3; ++u) {
                    const int j = sA + u * 4;
                    if (j < 10) {
                        uint4 a  = *((const uint4*)(row + j * 16));
                        uint4 bq = *((const uint4*)(row + j * 16 + 8));
                        const float* vv = &sv[j * 16];
                        float dj = h2f((u16)(a.x & 0xffff)) * vv[0]  + h2f((u16)(a.x >> 16)) * vv[1]
                                 + h2f((u16)(a.y & 0xffff)) * vv[2]  + h2f((u16)(a.y >> 16)) * vv[3]
                                 + h2f((u16)(a.z & 0xffff)) * vv[4]  + h2f((u16)(a.z >> 16)) * vv[5]
                                 + h2f((u16)(a.w & 0xffff)) * vv[6]  + h2f((u16)(a.w >> 16)) * vv[7]
                                 + h2f((u16)(bq.x & 0xffff)) * vv[8]  + h2f((u16)(bq.x >> 16)) * vv[9]
                                 + h2f((u16)(bq.y & 0xffff)) * vv[10] + h2f((u16)(bq.y >> 16)) * vv[11]
                                 + h2f((u16)(bq.z & 0xffff)) * vv[12] + h2f((u16)(bq.z >> 16)) * vv[13]
                                 + h2f((u16)(bq.w & 0xffff)) * vv[14] + h2f((u16)(bq.w >> 16)) * vv[15];
                        float nb = blrow[j] + dj;
                        blrow[j] = nb;
                        bj[u] = nb;
                        lmax = fmaxf(lmax, nb);
                    }
                }
                // row max across the 4 consecutive lanes (exact)
                lmax = fmaxf(lmax, __shfl_xor(lmax, 1, 64));
                lmax = fmaxf(lmax, __shfl_xor(lmax, 2, 64));
                float lsum = 0.f;
#pragma unroll
                for (int u = 0; u < 3; ++u) {
                    const int j = sA + u * 4;
                    if (j < 10) { bj[u] = __expf(bj[u] - lmax); lsum += bj[u]; }
                }
                lsum += __shfl_xor(lsum, 1, 64);
                lsum += __shfl_xor(lsum, 2, 64);
                const float inv = 1.f / lsum;
#pragma unroll
                for (int u = 0; u < 3; ++u) {
                    const int j = sA + u * 4;
                    if (j < 10) cl[j * 96 + rA] = bj[u] * inv;
                }
            }
            __syncthreads();               // cl visible
            if (t < 320) {                 // phase B: 48 rows, 4-way split acc
                const int r0 = hB * 48;
                const float* clj = &cl[jB * 96 + r0];
                const u16* up = uhs[p] + r0 * 168 + je;
#pragma unroll 3
                for (int il = 0; il < 48; il += 4) {
                    b0a = fmaf(clj[il],     h2f(up[(il)     * 168]), b0a);
                    b1a = fmaf(clj[il + 1], h2f(up[(il + 1) * 168]), b1a);
                    b2a = fmaf(clj[il + 2], h2f(up[(il + 2) * 168]), b2a);
                    b3a = fmaf(clj[il + 3], h2f(up[(il + 3) * 168]), b3a);
                }
            }
            if (!last) {                   // write next chunk into the other buffer
#pragma unroll
                for (int q = 0; q < 5; ++q) {
                    int v = t + q * 384, r = v / 20, c16 = v - r * 20;
                    *((uint4*)(&uhs[p ^ 1][r * 168 + c16 * 8])) = rg[q];
                }
            }
        }
        __syncthreads();
        if (t < 320) part[t] = (b0a + b1a) + (b2a + b3a);
        __syncthreads();
        if (t < 160) sv[t] = part[t] + part[t + 160];
        __syncthreads();
        if (t < 10) {
            float n2 = 0.f;
#pragma unroll
            for (int e2 = 0; e2 < 16; ++e2) { float xx = sv[t * 16 + e2]; n2 += xx * xx; }
            float n = sqrtf(n2);
            float f = n / (n2 + 1.f);
#pragma unroll
            for (int e2 = 0; e2 < 16; ++e2) sv[t * 16 + e2] *= f;
        }
    }
    __syncthreads();
    if (t < 160) out[(size_t)b * 160 + t] = sv[t];
}

extern "C" void kernel_launch(void* const* d_in, const int* in_sizes, int n_in,
                              void* d_out, int out_size, void* d_ws, size_t ws_size,
                              hipStream_t stream) {
    const float* x   = (const float*)d_in[0];
    const float* w1  = (const float*)d_in[1];
    const float* b1  = (const float*)d_in[2];
    const float* g1  = (const float*)d_in[3];
    const float* be1 = (const float*)d_in[4];
    const float* w2  = (const float*)d_in[5];
    const float* b2  = (const float*)d_in[6];
    const float* g2  = (const float*)d_in[7];
    const float* be2 = (const float*)d_in[8];
    const float* W   = (const float*)d_in[9];
    float* out = (float*)d_out;

    // ---- workspace layout (peak 213,524,480 B == proven-safe bound) ----
    const size_t OFF_UHAT = 8192;                       // 188,743,680 B (fp16, full batch)
    const size_t OFF_Y    = 8192;                       // 104,857,600 B (in u_hat region)
    const size_t OFF_W2R  = 104865792ull;               //  10,616,832 B (in u_hat region)
    const size_t OFF_Z    = 126099456ull;               //  18,874,368 B (in u_hat region)
    const size_t OFF_S0   = 198189056ull;               //     327,680 B (s0)
    const size_t OFF_WT   = 207626240ull;               //   5,898,240 B
    const size_t WS_NEED  = 213524480ull;
    if (ws_size < WS_NEED) return;

    char* ws = (char*)d_ws;
    float* sum1   = (float*)(ws + 0);
    float* sumsq1 = (float*)(ws + 1024);
    float* sum2   = (float*)(ws + 2048);
    float* sumsq2 = (float*)(ws + 3072);
    u16*   y     = (u16*)(ws + OFF_Y);
    u16*   w2r   = (u16*)(ws + OFF_W2R);
    float* z_raw = (float*)(ws + OFF_Z);
    float* s0g   = (float*)(ws + OFF_S0);
    float* Wt2   = (float*)(ws + OFF_WT);
    u16*   u_hat = (u16*)(ws + OFF_UHAT);

    hipMemsetAsync(ws, 0, 4096, stream);               // BN sums (must precede prep's atomics)

    hipLaunchKernelGGL(prep_kernel, dim3(27328), dim3(256), 0, stream,
                       x, w1, b1, y, sum1, sumsq1, w2, w2r, W, Wt2, s0g);
    hipLaunchKernelGGL(conv2_mfma_kernel, dim3(512), dim3(256), 0, stream,
                       y, w2r, b2, sum1, sumsq1, g1, be1, z_raw, sum2, sumsq2);
    hipLaunchKernelGGL(uhat_kernel,   dim3(512),   dim3(256), 0, stream,
                       z_raw, sum2, sumsq2, g2, be2, Wt2, u_hat, s0g);
    hipLaunchKernelGGL(routing_kernel, dim3(512),  dim3(384), 0, stream,
                       u_hat, s0g, out);
}